// Round 23
// baseline (117.060 us; speedup 1.0000x reference)
//
#include <hip/hip_runtime.h>
#include <math.h>

// ---------------------------------------------------------------------------
// MessageGenerator: edge-softmax attention message passing + MLP head.
// N=20000 nodes, E=200000 edges, D=512, Dm=256, Dh=128, H=512.
// R1-R21: see history. R20/R21 = 116.6-116.8us (best).
// gemm1_edge pinned at ~41us, invariant to A-bytes/TLP/order/atomics/ILP;
// nothing saturated -> suspect: per-K-step barrier drain (compiler emits
// s_waitcnt vmcnt(0) before every s_barrier; 8 drains/block serialize the
// load queue). R22: BK=128 (2 K-steps staged per barrier) -> 4 drains,
// 2x loads in flight per phase. LDS 24->48KB (still 3 blocks/CU).
// ---------------------------------------------------------------------------

typedef __attribute__((ext_vector_type(8))) short short8;
typedef __attribute__((ext_vector_type(4))) float f32x4;

#define M_SHIFT 4.75f  // const softmax shift; only couples via +1e-6 eps
#define RS_SCALE 1099511627776.0  // 2^40
#define RS_MASK ((1ULL << 49) - 1)

static __device__ __forceinline__ unsigned short f2bf(float f) {
  union { float f; unsigned int u; } v; v.f = f;
  unsigned int r = v.u + 0x7fffu + ((v.u >> 16) & 1u);  // round-nearest-even
  return (unsigned short)(r >> 16);
}
static __device__ __forceinline__ float bf2f(unsigned short b) {
  union { unsigned int u; float f; } v; v.u = ((unsigned int)b) << 16;
  return v.f;
}

// Zero one dword region + transpose/convert all three weights. One launch.
__global__ void init_kernel(unsigned int* __restrict__ z1, int n1,
                            const float* __restrict__ Wm,
                            short* __restrict__ WmT,
                            const float* __restrict__ W1,
                            short* __restrict__ W1T,
                            const float* __restrict__ W2,
                            short* __restrict__ W2T) {
  int i = blockIdx.x * 256 + threadIdx.x;
  int stride = gridDim.x * 256;
  for (int j = i; j < n1; j += stride) z1[j] = 0u;
  if (i < 131072) {
    int n = i >> 9, k = i & 511;  // K=512, N=256
    WmT[i] = (short)f2bf(Wm[(size_t)k * 256 + n]);
  } else if (i < 196608) {
    int j = i - 131072;
    int n = j >> 9, k = j & 511;  // K=512, N=128
    W1T[j] = (short)f2bf(W1[(size_t)k * 128 + n]);
  } else if (i < 262144) {
    int j = i - 196608;
    int n = j >> 7, k = j & 127;  // K=128, N=512
    W2T[j] = (short)f2bf(W2[(size_t)k * 512 + n]);
  }
}

// Fused: blocks [0, edgeBlocks) run edge_exp (2 edges/thread, FIRST); rest
// run GEMM1 (NT=2, BK=128: two K-steps staged per barrier).
__global__ __launch_bounds__(512) void gemm1_edge_kernel(
    const float* __restrict__ Av, const short* __restrict__ Bt,
    const float* __restrict__ bias, unsigned short* __restrict__ Cv, int M,
    int edgeBlocks, const float* __restrict__ gate,
    const int* __restrict__ idx, float* __restrict__ exp_e,
    unsigned long long* __restrict__ combined, int* __restrict__ deg_dst,
    int* __restrict__ rank_src, int* __restrict__ rank_dst, int E) {
  const int N = 256, K = 512;
  __shared__ short As[2][64 * 64];       // 16 KB (2 K-halves)
  __shared__ short Bs[2][2 * 64 * 64];   // 32 KB (2 K-halves x 128 n-rows)
  if ((int)blockIdx.x < edgeBlocks) {
    // --- edge_exp part: 2 edges/thread ---
    int base = (int)blockIdx.x * 1024;
    int e0 = base + threadIdx.x;
    int e1 = e0 + 512;
    bool v0ok = e0 < E, v1ok = e1 < E;
    float g0 = v0ok ? gate[e0] : 0.f;
    float g1 = v1ok ? gate[e1] : 0.f;
    int s0 = 0, d0 = 0, s1 = 0, d1 = 0;
    if (v0ok) { s0 = idx[2 * e0]; d0 = idx[2 * e0 + 1]; }
    if (v1ok) { s1 = idx[2 * e1]; d1 = idx[2 * e1 + 1]; }
    float v0 = expf(g0 - M_SHIFT);
    float v1 = expf(g1 - M_SHIFT);
    unsigned long long oldc0 = 0, oldc1 = 0;
    int oldd0 = 0, oldd1 = 0;
    if (v0ok) {
      unsigned long long fx = (unsigned long long)((double)v0 * RS_SCALE);
      oldc0 = atomicAdd(&combined[s0], (1ULL << 49) | fx);
      oldd0 = atomicAdd(&deg_dst[d0], 1);
    }
    if (v1ok) {
      unsigned long long fx = (unsigned long long)((double)v1 * RS_SCALE);
      oldc1 = atomicAdd(&combined[s1], (1ULL << 49) | fx);
      oldd1 = atomicAdd(&deg_dst[d1], 1);
    }
    if (v0ok) {
      exp_e[e0] = v0;
      rank_src[e0] = (int)(oldc0 >> 49);
      rank_dst[e0] = oldd0;
    }
    if (v1ok) {
      exp_e[e1] = v1;
      rank_src[e1] = (int)(oldc1 >> 49);
      rank_dst[e1] = oldd1;
    }
    return;
  }
  // --- GEMM1 part (fp32 A converted in staging, NT=2, BK=128) ---
  int tid = threadIdx.x;
  int lane = tid & 63, wid = tid >> 6;
  int wm = wid >> 2, wn = wid & 3;
  int blk = (int)blockIdx.x - edgeBlocks;
  int m0 = (blk >> 1) * 64;
  int n0 = (blk & 1) * 128;

  f32x4 acc[2][2];
#pragma unroll
  for (int m = 0; m < 2; ++m)
#pragma unroll
    for (int n = 0; n < 2; ++n) acc[m][n] = (f32x4){0.f, 0.f, 0.f, 0.f};

  int ar = tid >> 3, ag = tid & 7;
  bool arow_ok = (m0 + ar) < M;

  for (int k0 = 0; k0 < K; k0 += 128) {
    // stage BOTH K-halves before one barrier (2x loads in flight)
#pragma unroll
    for (int h = 0; h < 2; ++h) {
      const float4* ap =
          (const float4*)(Av + (size_t)(m0 + ar) * K + k0 + h * 64 + ag * 8);
      float4 u = make_float4(0.f, 0.f, 0.f, 0.f);
      float4 v = make_float4(0.f, 0.f, 0.f, 0.f);
      if (arow_ok) { u = ap[0]; v = ap[1]; }
      short8 w;
      w[0] = (short)f2bf(u.x); w[1] = (short)f2bf(u.y);
      w[2] = (short)f2bf(u.z); w[3] = (short)f2bf(u.w);
      w[4] = (short)f2bf(v.x); w[5] = (short)f2bf(v.y);
      w[6] = (short)f2bf(v.z); w[7] = (short)f2bf(v.w);
      *(short8*)&As[h][ar * 64 + ((ag ^ (ar & 7)) << 3)] = w;
#pragma unroll
      for (int nt = 0; nt < 2; ++nt) {
        int r = nt * 64 + ar;
        const short8* bp =
            (const short8*)(Bt + (size_t)(n0 + r) * K + k0 + h * 64);
        short8 wb = bp[ag];
        *(short8*)&Bs[h][r * 64 + ((ag ^ (r & 7)) << 3)] = wb;
      }
    }
    __syncthreads();
    int lsw = lane & 7, l15 = lane & 15, lk = lane >> 4;
#pragma unroll
    for (int h = 0; h < 2; ++h) {
#pragma unroll
      for (int kk = 0; kk < 2; ++kk) {
        int gg = kk * 4 + lk;
        int xo = ((gg ^ lsw) << 3);
        short8 af[2];
#pragma unroll
        for (int m = 0; m < 2; ++m)
          af[m] = *(const short8*)&As[h][(wm * 32 + m * 16 + l15) * 64 + xo];
#pragma unroll
        for (int f = 0; f < 2; ++f) {
          short8 bfr =
              *(const short8*)&Bs[h][(wn * 32 + f * 16 + l15) * 64 + xo];
#pragma unroll
          for (int m = 0; m < 2; ++m)
            acc[m][f] = __builtin_amdgcn_mfma_f32_16x16x32_bf16(
                af[m], bfr, acc[m][f], 0, 0, 0);
        }
      }
    }
    __syncthreads();
  }
#pragma unroll
  for (int m = 0; m < 2; ++m) {
    int gmBase = m0 + wm * 32 + m * 16 + (lane >> 4) * 4;
#pragma unroll
    for (int f = 0; f < 2; ++f) {
      int gn = n0 + wn * 32 + f * 16 + (lane & 15);
      float bv = bias[gn];
#pragma unroll
      for (int r = 0; r < 4; ++r) {
        int gm = gmBase + r;
        if (gm >= M) continue;
        Cv[(size_t)gm * N + gn] = f2bf(acc[m][f][r] + bv);
      }
    }
  }
}

// Phase 1: decode combined -> (deg_src, row_sum); per-block exclusive scan.
__global__ __launch_bounds__(1024) void scan_part_kernel(
    const unsigned long long* __restrict__ combined,
    const int* __restrict__ degB, float* __restrict__ row_sum,
    int* __restrict__ offA, int* __restrict__ offB, int* __restrict__ sumsA,
    int* __restrict__ sumsB, int n) {
  __shared__ int tA[1024], tB[1024];
  int b = blockIdx.x, t = threadIdx.x;
  int i = b * 1024 + t;
  int vA = 0, vB = 0;
  if (i < n) {
    unsigned long long c = combined[i];
    vA = (int)(c >> 49);
    row_sum[i] = (float)((double)(c & RS_MASK) * (1.0 / RS_SCALE));
    vB = degB[i];
  }
  tA[t] = vA;
  tB[t] = vB;
  __syncthreads();
  for (int off = 1; off < 1024; off <<= 1) {
    int xA = (t >= off) ? tA[t - off] : 0;
    int xB = (t >= off) ? tB[t - off] : 0;
    __syncthreads();
    tA[t] += xA;
    tB[t] += xB;
    __syncthreads();
  }
  if (i < n) {
    offA[i] = tA[t] - vA;  // block-local exclusive
    offB[i] = tB[t] - vB;
  }
  if (t == 1023) {
    sumsA[b] = tA[t];
    sumsB[b] = tB[t];
  }
}

// Phase 2: add carry of preceding blocks.
__global__ __launch_bounds__(1024) void scan_fixup_kernel(
    int* __restrict__ offA, int* __restrict__ offB,
    const int* __restrict__ sumsA, const int* __restrict__ sumsB, int n,
    int nb) {
  __shared__ int cA, cB;
  int b = blockIdx.x, t = threadIdx.x;
  if (t == 0) {
    int ca = 0, cb = 0;
    for (int j = 0; j < b; ++j) {
      ca += sumsA[j];
      cb += sumsB[j];
    }
    cA = ca;
    cB = cb;
  }
  __syncthreads();
  int i = b * 1024 + t;
  if (i < n) {
    offA[i] += cA;
    offB[i] += cB;
  }
  if (b == nb - 1 && t == 0) {
    offA[n] = cA + sumsA[b];
    offB[n] = cB + sumsB[b];
  }
}

// Scatter edges into both CSR lists via precomputed ranks — NO atomics.
// 2 edges/thread.
__global__ void scatter_ids_kernel(const int* __restrict__ idx,
                                   const float* __restrict__ exp_e,
                                   const float* __restrict__ row_sum,
                                   const int* __restrict__ off_src,
                                   const int* __restrict__ off_dst,
                                   const int* __restrict__ rank_src,
                                   const int* __restrict__ rank_dst,
                                   int* __restrict__ oth_src,
                                   float* __restrict__ att_src,
                                   int* __restrict__ oth_dst,
                                   float* __restrict__ att_dst, int E) {
  int base = blockIdx.x * 512;
  int e0 = base + threadIdx.x;
  int e1 = e0 + 256;
#pragma unroll
  for (int k = 0; k < 2; ++k) {
    int e = k ? e1 : e0;
    if (e >= E) continue;
    int s = idx[2 * e], d = idx[2 * e + 1];
    float a = exp_e[e] / (row_sum[s] + 1e-6f);
    int p = off_src[s] + rank_src[e];
    oth_src[p] = d;
    att_src[p] = a;
    int q = off_dst[d] + rank_dst[e];
    oth_dst[q] = s;
    att_dst[q] = a;
  }
}

// One wave per (node, direction); unroll ladder 8/4/2/1 keeps >=2 gathers
// in flight through the tail (mean degree 10).
__global__ __launch_bounds__(256) void aggregate_kernel(
    const int* __restrict__ off_src, const int* __restrict__ oth_src,
    const float* __restrict__ att_src, const int* __restrict__ off_dst,
    const int* __restrict__ oth_dst, const float* __restrict__ att_dst,
    const unsigned short* __restrict__ Mfeat, unsigned short* __restrict__ msg,
    int Nn) {
  int slot = blockIdx.x * 4 + (threadIdx.x >> 6);
  int node = slot >> 1, dir = slot & 1;
  if (node >= Nn) return;
  int lane = threadIdx.x & 63;
  const int* offp = dir ? off_dst : off_src;
  const int* othp = dir ? oth_dst : oth_src;
  const float* attp = dir ? att_dst : att_src;
  float ax = 0.f, ay = 0.f, az = 0.f, aw_ = 0.f;
  int b0 = offp[node], e0 = offp[node + 1];
  for (int base = b0; base < e0; base += 64) {
    int cnt = min(64, e0 - base);
    int oth = (lane < cnt) ? othp[base + lane] : 0;
    float wv = (lane < cnt) ? attp[base + lane] : 0.0f;
    int t = 0;
    for (; t + 8 <= cnt; t += 8) {
      int r0 = __shfl(oth, t, 64), r1 = __shfl(oth, t + 1, 64);
      int r2 = __shfl(oth, t + 2, 64), r3 = __shfl(oth, t + 3, 64);
      int r4 = __shfl(oth, t + 4, 64), r5 = __shfl(oth, t + 5, 64);
      int r6 = __shfl(oth, t + 6, 64), r7 = __shfl(oth, t + 7, 64);
      float w0 = __shfl(wv, t, 64), w1 = __shfl(wv, t + 1, 64);
      float w2 = __shfl(wv, t + 2, 64), w3 = __shfl(wv, t + 3, 64);
      float w4 = __shfl(wv, t + 4, 64), w5 = __shfl(wv, t + 5, 64);
      float w6 = __shfl(wv, t + 6, 64), w7 = __shfl(wv, t + 7, 64);
      ushort4 m0 = *((const ushort4*)(Mfeat + (size_t)r0 * 256) + lane);
      ushort4 m1 = *((const ushort4*)(Mfeat + (size_t)r1 * 256) + lane);
      ushort4 m2 = *((const ushort4*)(Mfeat + (size_t)r2 * 256) + lane);
      ushort4 m3 = *((const ushort4*)(Mfeat + (size_t)r3 * 256) + lane);
      ushort4 m4 = *((const ushort4*)(Mfeat + (size_t)r4 * 256) + lane);
      ushort4 m5 = *((const ushort4*)(Mfeat + (size_t)r5 * 256) + lane);
      ushort4 m6 = *((const ushort4*)(Mfeat + (size_t)r6 * 256) + lane);
      ushort4 m7 = *((const ushort4*)(Mfeat + (size_t)r7 * 256) + lane);
      ax = fmaf(w0, bf2f(m0.x), ax); ay = fmaf(w0, bf2f(m0.y), ay);
      az = fmaf(w0, bf2f(m0.z), az); aw_ = fmaf(w0, bf2f(m0.w), aw_);
      ax = fmaf(w1, bf2f(m1.x), ax); ay = fmaf(w1, bf2f(m1.y), ay);
      az = fmaf(w1, bf2f(m1.z), az); aw_ = fmaf(w1, bf2f(m1.w), aw_);
      ax = fmaf(w2, bf2f(m2.x), ax); ay = fmaf(w2, bf2f(m2.y), ay);
      az = fmaf(w2, bf2f(m2.z), az); aw_ = fmaf(w2, bf2f(m2.w), aw_);
      ax = fmaf(w3, bf2f(m3.x), ax); ay = fmaf(w3, bf2f(m3.y), ay);
      az = fmaf(w3, bf2f(m3.z), az); aw_ = fmaf(w3, bf2f(m3.w), aw_);
      ax = fmaf(w4, bf2f(m4.x), ax); ay = fmaf(w4, bf2f(m4.y), ay);
      az = fmaf(w4, bf2f(m4.z), az); aw_ = fmaf(w4, bf2f(m4.w), aw_);
      ax = fmaf(w5, bf2f(m5.x), ax); ay = fmaf(w5, bf2f(m5.y), ay);
      az = fmaf(w5, bf2f(m5.z), az); aw_ = fmaf(w5, bf2f(m5.w), aw_);
      ax = fmaf(w6, bf2f(m6.x), ax); ay = fmaf(w6, bf2f(m6.y), ay);
      az = fmaf(w6, bf2f(m6.z), az); aw_ = fmaf(w6, bf2f(m6.w), aw_);
      ax = fmaf(w7, bf2f(m7.x), ax); ay = fmaf(w7, bf2f(m7.y), ay);
      az = fmaf(w7, bf2f(m7.z), az); aw_ = fmaf(w7, bf2f(m7.w), aw_);
    }
    for (; t + 4 <= cnt; t += 4) {
      int r0 = __shfl(oth, t, 64), r1 = __shfl(oth, t + 1, 64);
      int r2 = __shfl(oth, t + 2, 64), r3 = __shfl(oth, t + 3, 64);
      float w0 = __shfl(wv, t, 64), w1 = __shfl(wv, t + 1, 64);
      float w2 = __shfl(wv, t + 2, 64), w3 = __shfl(wv, t + 3, 64);
      ushort4 m0 = *((const ushort4*)(Mfeat + (size_t)r0 * 256) + lane);
      ushort4 m1 = *((const ushort4*)(Mfeat + (size_t)r1 * 256) + lane);
      ushort4 m2 = *((const ushort4*)(Mfeat + (size_t)r2 * 256) + lane);
      ushort4 m3 = *((const ushort4*)(Mfeat + (size_t)r3 * 256) + lane);
      ax = fmaf(w0, bf2f(m0.x), ax); ay = fmaf(w0, bf2f(m0.y), ay);
      az = fmaf(w0, bf2f(m0.z), az); aw_ = fmaf(w0, bf2f(m0.w), aw_);
      ax = fmaf(w1, bf2f(m1.x), ax); ay = fmaf(w1, bf2f(m1.y), ay);
      az = fmaf(w1, bf2f(m1.z), az); aw_ = fmaf(w1, bf2f(m1.w), aw_);
      ax = fmaf(w2, bf2f(m2.x), ax); ay = fmaf(w2, bf2f(m2.y), ay);
      az = fmaf(w2, bf2f(m2.z), az); aw_ = fmaf(w2, bf2f(m2.w), aw_);
      ax = fmaf(w3, bf2f(m3.x), ax); ay = fmaf(w3, bf2f(m3.y), ay);
      az = fmaf(w3, bf2f(m3.z), az); aw_ = fmaf(w3, bf2f(m3.w), aw_);
    }
    for (; t + 2 <= cnt; t += 2) {
      int r0 = __shfl(oth, t, 64), r1 = __shfl(oth, t + 1, 64);
      float w0 = __shfl(wv, t, 64), w1 = __shfl(wv, t + 1, 64);
      ushort4 m0 = *((const ushort4*)(Mfeat + (size_t)r0 * 256) + lane);
      ushort4 m1 = *((const ushort4*)(Mfeat + (size_t)r1 * 256) + lane);
      ax = fmaf(w0, bf2f(m0.x), ax); ay = fmaf(w0, bf2f(m0.y), ay);
      az = fmaf(w0, bf2f(m0.z), az); aw_ = fmaf(w0, bf2f(m0.w), aw_);
      ax = fmaf(w1, bf2f(m1.x), ax); ay = fmaf(w1, bf2f(m1.y), ay);
      az = fmaf(w1, bf2f(m1.z), az); aw_ = fmaf(w1, bf2f(m1.w), aw_);
    }
    for (; t < cnt; ++t) {
      int r = __shfl(oth, t, 64);
      float w = __shfl(wv, t, 64);
      ushort4 mv = *((const ushort4*)(Mfeat + (size_t)r * 256) + lane);
      ax = fmaf(w, bf2f(mv.x), ax); ay = fmaf(w, bf2f(mv.y), ay);
      az = fmaf(w, bf2f(mv.z), az); aw_ = fmaf(w, bf2f(mv.w), aw_);
    }
  }
  ushort4 o;
  o.x = f2bf(ax); o.y = f2bf(ay); o.z = f2bf(az); o.w = f2bf(aw_);
  *((ushort4*)(msg + (size_t)node * 512 + dir * 256) + lane) = o;
}

// bf16 MFMA GEMM: C[M,N] = A[M,K] @ Bt[N,K]^T + bias. (GEMM3)
template <int ABF16, int OUT_MODE, int NT>
__global__ __launch_bounds__(512) void mfma_gemm_kernel(
    const void* __restrict__ Av, const short* __restrict__ Bt,
    const float* __restrict__ bias, const float* __restrict__ row_sum,
    void* __restrict__ Cv, int M, int N, int K) {
  __shared__ short As[64 * 64];
  __shared__ short Bs[NT * 64 * 64];
  int tid = threadIdx.x;
  int lane = tid & 63, wid = tid >> 6;  // 8 waves
  int wm = wid >> 2, wn = wid & 3;      // 2 x 4
  int m0 = blockIdx.x * 64, n0 = blockIdx.y * (64 * NT);

  f32x4 acc[2][NT];
#pragma unroll
  for (int m = 0; m < 2; ++m)
#pragma unroll
    for (int n = 0; n < NT; ++n) acc[m][n] = (f32x4){0.f, 0.f, 0.f, 0.f};

  int ar = tid >> 3;
  int ag = tid & 7;
  bool arow_ok = (m0 + ar) < M;

  for (int k0 = 0; k0 < K; k0 += 64) {
    if (ABF16) {
      const short8* ap =
          (const short8*)((const short*)Av + (size_t)(m0 + ar) * K + k0);
      short8 w = (short8){0, 0, 0, 0, 0, 0, 0, 0};
      if (arow_ok) w = ap[ag];
      *(short8*)&As[ar * 64 + ((ag ^ (ar & 7)) << 3)] = w;
    } else {
      const float4* ap =
          (const float4*)((const float*)Av + (size_t)(m0 + ar) * K + k0 + ag * 8);
      float4 u = make_float4(0.f, 0.f, 0.f, 0.f);
      float4 v = make_float4(0.f, 0.f, 0.f, 0.f);
      if (arow_ok) { u = ap[0]; v = ap[1]; }
      short8 w;
      w[0] = (short)f2bf(u.x); w[1] = (short)f2bf(u.y);
      w[2] = (short)f2bf(u.z); w[3] = (short)f2bf(u.w);
      w[4] = (short)f2bf(v.x); w[5] = (short)f2bf(v.y);
      w[6] = (short)f2bf(v.z); w[7] = (short)f2bf(v.w);
      *(short8*)&As[ar * 64 + ((ag ^ (ar & 7)) << 3)] = w;
    }
#pragma unroll
    for (int nt = 0; nt < NT; ++nt) {
      int r = nt * 64 + ar;
      const short8* bp = (const short8*)(Bt + (size_t)(n0 + r) * K + k0);
      short8 w = bp[ag];
      *(short8*)&Bs[r * 64 + ((ag ^ (r & 7)) << 3)] = w;
    }
    __syncthreads();
    int lsw = lane & 7, l15 = lane & 15, lk = lane >> 4;
#pragma unroll
    for (int kk = 0; kk < 2; ++kk) {
      int gg = kk * 4 + lk;
      int xo = ((gg ^ lsw) << 3);
      short8 af[2];
#pragma unroll
      for (int m = 0; m < 2; ++m)
        af[m] = *(const short8*)&As[(wm * 32 + m * 16 + l15) * 64 + xo];
#pragma unroll
      for (int f = 0; f < NT; ++f) {
        short8 bfr =
            *(const short8*)&Bs[(wn * NT * 16 + f * 16 + l15) * 64 + xo];
#pragma unroll
        for (int m = 0; m < 2; ++m)
          acc[m][f] = __builtin_amdgcn_mfma_f32_16x16x32_bf16(af[m], bfr,
                                                              acc[m][f], 0, 0, 0);
      }
    }
    __syncthreads();
  }
#pragma unroll
  for (int m = 0; m < 2; ++m) {
    int gmBase = m0 + wm * 32 + m * 16 + (lane >> 4) * 4;
#pragma unroll
    for (int f = 0; f < NT; ++f) {
      int gn = n0 + wn * NT * 16 + f * 16 + (lane & 15);
      float bv = bias[gn];
#pragma unroll
      for (int r = 0; r < 4; ++r) {
        int gm = gmBase + r;
        if (gm >= M) continue;
        float v = acc[m][f][r] + bv;
        if (OUT_MODE == 1) v = (row_sum[gm] > 0.0f) ? fmaxf(v, 0.0f) : 0.0f;
        if (OUT_MODE == 2)
          ((unsigned short*)Cv)[(size_t)gm * N + gn] = f2bf(v);
        else
          ((float*)Cv)[(size_t)gm * N + gn] = v;
      }
    }
  }
}

// GEMM2 fused with LayerNorm+ReLU: h1ln(bf16) = relu(LN(msg @ W1 + b1)).
__global__ __launch_bounds__(512) void gemm2_ln_kernel(
    const unsigned short* __restrict__ msg, const short* __restrict__ W1T,
    const float* __restrict__ b1, const float* __restrict__ gamma,
    const float* __restrict__ beta, unsigned short* __restrict__ h1ln,
    int M) {
  __shared__ short As[64 * 64];
  __shared__ short Bs[128 * 64];
  __shared__ float lnS[64][4];
  __shared__ float lnQ[64][4];
  const int K = 512;
  int tid = threadIdx.x;
  int lane = tid & 63, wid = tid >> 6;  // 8 waves
  int wm = wid >> 2, wn = wid & 3;      // 2m x 4n (4n x 32 cols = 128)
  int m0 = blockIdx.x * 64;

  f32x4 acc[2][2];
#pragma unroll
  for (int m = 0; m < 2; ++m)
#pragma unroll
    for (int n = 0; n < 2; ++n) acc[m][n] = (f32x4){0.f, 0.f, 0.f, 0.f};

  int ar = tid >> 3, ag = tid & 7;
  bool arow_ok = (m0 + ar) < M;
  int br = tid >> 2;       // B row 0..127
  int bg = (tid & 3) * 2;  // 2 k-groups each

  for (int k0 = 0; k0 < K; k0 += 64) {
    {
      const short8* ap =
          (const short8*)((const short*)msg + (size_t)(m0 + ar) * K + k0);
      short8 w = (short8){0, 0, 0, 0, 0, 0, 0, 0};
      if (arow_ok) w = ap[ag];
      *(short8*)&As[ar * 64 + ((ag ^ (ar & 7)) << 3)] = w;
    }
    {
      const short8* bp = (const short8*)(W1T + (size_t)br * K + k0);
#pragma unroll
      for (int g2 = 0; g2 < 2; ++g2) {
        int g = bg + g2;
        short8 w = bp[g];
        *(short8*)&Bs[br * 64 + ((g ^ (br & 7)) << 3)] = w;
      }
    }
    __syncthreads();
    int lsw = lane & 7, l15 = lane & 15, lk = lane >> 4;
#pragma unroll
    for (int kk = 0; kk < 2; ++kk) {
      int gg = kk * 4 + lk;
      int xo = ((gg ^ lsw) << 3);
      short8 af[2];
#pragma unroll
      for (int m = 0; m < 2; ++m)
        af[m] = *(const short8*)&As[(wm * 32 + m * 16 + l15) * 64 + xo];
#pragma unroll
      for (int n = 0; n < 2; ++n) {
        short8 bfr = *(const short8*)&Bs[(wn * 32 + n * 16 + l15) * 64 + xo];
#pragma unroll
        for (int m = 0; m < 2; ++m)
          acc[m][n] = __builtin_amdgcn_mfma_f32_16x16x32_bf16(af[m], bfr,
                                                              acc[m][n], 0, 0, 0);
      }
    }
    __syncthreads();
  }

  // --- LN epilogue ---
  int l15 = lane & 15, lg = lane >> 4;
  int c0 = wn * 32 + l15, c1 = c0 + 16;
  float bv0 = b1[c0], bv1 = b1[c1];
  float g0 = gamma[c0], g1 = gamma[c1];
  float be0 = beta[c0], be1 = beta[c1];
#pragma unroll
  for (int m = 0; m < 2; ++m) {
#pragma unroll
    for (int r = 0; r < 4; ++r) {
      float v0 = acc[m][0][r] + bv0, v1 = acc[m][1][r] + bv1;
      float s1 = v0 + v1;
      float s2 = v0 * v0 + v1 * v1;
#pragma unroll
      for (int mk = 1; mk < 16; mk <<= 1) {
        s1 += __shfl_xor(s1, mk, 64);
        s2 += __shfl_xor(s2, mk, 64);
      }
      int row_l = wm * 32 + m * 16 + lg * 4 + r;
      if (l15 == 0) {
        lnS[row_l][wn] = s1;
        lnQ[row_l][wn] = s2;
      }
    }
  }
  __syncthreads();
#pragma unroll
  for (int m = 0; m < 2; ++m) {
#pragma unroll
    for (int r = 0; r < 4; ++r) {
      int row_l = wm * 32 + m * 16 + lg * 4 + r;
      int gm = m0 + row_l;
      if (gm >= M) continue;
      float S = lnS[row_l][0] + lnS[row_l][1] + lnS[row_l][2] + lnS[row_l][3];
      float Q = lnQ[row_l][0] + lnQ[row_l][1] + lnQ[row_l][2] + lnQ[row_l][3];
      float mu = S * 0.0078125f;             // /128
      float var = Q * 0.0078125f - mu * mu;  // E[x^2]-mu^2
      float rs = rsqrtf(var + 1e-5f);
      float v0 = acc[m][0][r] + bv0, v1 = acc[m][1][r] + bv1;
      float y0 = fmaxf((v0 - mu) * rs * g0 + be0, 0.0f);
      float y1 = fmaxf((v1 - mu) * rs * g1 + be1, 0.0f);
      h1ln[(size_t)gm * 128 + c0] = f2bf(y0);
      h1ln[(size_t)gm * 128 + c1] = f2bf(y1);
    }
  }
}

extern "C" void kernel_launch(void* const* d_in, const int* in_sizes, int n_in,
                              void* d_out, int out_size, void* d_ws,
                              size_t ws_size, hipStream_t stream) {
  const float* src_feat = (const float*)d_in[0];
  const float* gate = (const float*)d_in[1];
  const int* idx = (const int*)d_in[2];
  const float* Wm = (const float*)d_in[3];
  const float* bm = (const float*)d_in[4];
  const float* W1 = (const float*)d_in[5];
  const float* b1 = (const float*)d_in[6];
  const float* gamma = (const float*)d_in[7];
  const float* beta = (const float*)d_in[8];
  const float* W2 = (const float*)d_in[9];
  const float* b2 = (const float*)d_in[10];
  float* out = (float*)d_out;

  const int D = 512;
  const int Nn = in_sizes[0] / D;  // 20000
  const int E = in_sizes[1];       // 200000

  char* ws = (char*)d_ws;
  size_t off = 0;
  auto alloc = [&](size_t bytes) {
    void* p = ws + off;
    off = (off + bytes + 255) & ~(size_t)255;
    return p;
  };
  // zero-region: combined (u64) + deg_dst (contiguous)
  unsigned long long* combined = (unsigned long long*)alloc((size_t)Nn * 8);
  int* deg_dst = (int*)alloc((size_t)Nn * 4);
  char* z_end = ws + off;
  float* row_sum = (float*)alloc((size_t)Nn * 4);  // written by scan_part
  float* exp_e = (float*)alloc((size_t)E * 4);
  int* rank_src = (int*)alloc((size_t)E * 4);
  int* rank_dst = (int*)alloc((size_t)E * 4);
  unsigned short* Mfeat = (unsigned short*)alloc((size_t)Nn * 256 * 2);
  unsigned short* msg = (unsigned short*)alloc((size_t)Nn * 512 * 2);
  unsigned short* h1ln = (unsigned short*)alloc((size_t)Nn * 128 * 2);
  short* WmT = (short*)alloc((size_t)512 * 256 * 2);
  short* W1T = (short*)alloc((size_t)512 * 128 * 2);
  short* W2T = (short*)alloc((size_t)128 * 512 * 2);
  int* off_src = (int*)alloc((size_t)(Nn + 1) * 4);
  int* off_dst = (int*)alloc((size_t)(Nn + 1) * 4);
  int* oth_src = (int*)alloc((size_t)E * 4);
  float* att_src = (float*)alloc((size_t)E * 4);
  int* oth_dst = (int*)alloc((size_t)E * 4);
  float* att_dst = (float*)alloc((size_t)E * 4);
  int* sumsA = (int*)alloc(64 * 4);
  int* sumsB = (int*)alloc(64 * 4);

  int n1 = (int)((z_end - (char*)combined) >> 2);
  init_kernel<<<1024, 256, 0, stream>>>((unsigned int*)combined, n1, Wm, WmT,
                                        W1, W1T, W2, W2T);

  int gx = (Nn + 63) / 64;            // 313
  int gemmBlocks = gx * 2;            // 626 (NT=2, 2 n-tiles)
  int edgeBlocks = (E + 1023) / 1024; // 196 (2 edges/thread)
  // edge_exp (196 blocks, FIRST) || GEMM1 (626 blocks, BK=128), one launch
  gemm1_edge_kernel<<<edgeBlocks + gemmBlocks, 512, 0, stream>>>(
      src_feat, WmT, bm, Mfeat, Nn, edgeBlocks, gate, idx, exp_e, combined,
      deg_dst, rank_src, rank_dst, E);

  int nb = (Nn + 1023) / 1024;  // 20
  scan_part_kernel<<<nb, 1024, 0, stream>>>(combined, deg_dst, row_sum,
                                            off_src, off_dst, sumsA, sumsB,
                                            Nn);
  scan_fixup_kernel<<<nb, 1024, 0, stream>>>(off_src, off_dst, sumsA, sumsB,
                                             Nn, nb);
  // scatter: NO atomics (rank-based slots), 2 edges/thread
  scatter_ids_kernel<<<(E + 511) / 512, 256, 0, stream>>>(
      idx, exp_e, row_sum, off_src, off_dst, rank_src, rank_dst, oth_src,
      att_src, oth_dst, att_dst, E);
  // aggregate: one wave per (node, dir) -> 40000 waves
  aggregate_kernel<<<(2 * Nn + 3) / 4, 256, 0, stream>>>(
      off_src, oth_src, att_src, off_dst, oth_dst, att_dst, Mfeat, msg, Nn);
  // GEMM2 + LN + ReLU fused: h1ln(bf16) = relu(LN(msg @ W1 + b1))
  gemm2_ln_kernel<<<gx, 512, 0, stream>>>(msg, W1T, b1, gamma, beta, h1ln, Nn);
  // GEMM3: out(f32) = h1ln(bf16) @ W2 + b2, relu+mask  [M=Nn,N=512,K=128],
  //        NT=4, y=2
  mfma_gemm_kernel<1, 1, 4><<<dim3(gx, 2), 512, 0, stream>>>(
      h1ln, W2T, b2, row_sum, out, Nn, 512, 128);
}

// Round 24
// 112.685 us; speedup vs baseline: 1.0388x; 1.0388x over previous
//
#include <hip/hip_runtime.h>
#include <math.h>

// ---------------------------------------------------------------------------
// MessageGenerator: edge-softmax attention message passing + MLP head.
// N=20000 nodes, E=200000 edges, D=512, Dm=256, Dh=128, H=512.
// R1-R22: see history. R21 = 116.6us (best).
// gemm1_edge invariance dossier: A-bytes(R14), TLP(R16), order(R18),
// atomics 3->2(R17), edge ILP(R21), BK=128(R22) — all ~null.
// R23: LAST structural hypothesis — role interleave. Edge blocks were a
//      contiguous grid prefix; dispatcher fills CUs class-by-class, so
//      atomic-bound and MFMA-bound blocks never co-reside -> no mutual
//      latency hiding (explains R15 serial==fused). Bresenham-interleave
//      edge/gemm roles across the grid. BK=64 (R21 body).
// ---------------------------------------------------------------------------

typedef __attribute__((ext_vector_type(8))) short short8;
typedef __attribute__((ext_vector_type(4))) float f32x4;

#define M_SHIFT 4.75f  // const softmax shift; only couples via +1e-6 eps
#define RS_SCALE 1099511627776.0  // 2^40
#define RS_MASK ((1ULL << 49) - 1)

static __device__ __forceinline__ unsigned short f2bf(float f) {
  union { float f; unsigned int u; } v; v.f = f;
  unsigned int r = v.u + 0x7fffu + ((v.u >> 16) & 1u);  // round-nearest-even
  return (unsigned short)(r >> 16);
}
static __device__ __forceinline__ float bf2f(unsigned short b) {
  union { unsigned int u; float f; } v; v.u = ((unsigned int)b) << 16;
  return v.f;
}

// Zero one dword region + transpose/convert all three weights. One launch.
__global__ void init_kernel(unsigned int* __restrict__ z1, int n1,
                            const float* __restrict__ Wm,
                            short* __restrict__ WmT,
                            const float* __restrict__ W1,
                            short* __restrict__ W1T,
                            const float* __restrict__ W2,
                            short* __restrict__ W2T) {
  int i = blockIdx.x * 256 + threadIdx.x;
  int stride = gridDim.x * 256;
  for (int j = i; j < n1; j += stride) z1[j] = 0u;
  if (i < 131072) {
    int n = i >> 9, k = i & 511;  // K=512, N=256
    WmT[i] = (short)f2bf(Wm[(size_t)k * 256 + n]);
  } else if (i < 196608) {
    int j = i - 131072;
    int n = j >> 9, k = j & 511;  // K=512, N=128
    W1T[j] = (short)f2bf(W1[(size_t)k * 128 + n]);
  } else if (i < 262144) {
    int j = i - 196608;
    int n = j >> 7, k = j & 127;  // K=128, N=512
    W2T[j] = (short)f2bf(W2[(size_t)k * 512 + n]);
  }
}

// Fused, role-INTERLEAVED: block bid is an edge block iff
// floor((bid+1)*nEdge/nTot) > floor(bid*nEdge/nTot)  (Bresenham), giving an
// even spatial mix of atomic-bound and MFMA-bound blocks across CUs.
__global__ __launch_bounds__(512) void gemm1_edge_kernel(
    const float* __restrict__ Av, const short* __restrict__ Bt,
    const float* __restrict__ bias, unsigned short* __restrict__ Cv, int M,
    int nEdge, int nTot, const float* __restrict__ gate,
    const int* __restrict__ idx, float* __restrict__ exp_e,
    unsigned long long* __restrict__ combined, int* __restrict__ deg_dst,
    int* __restrict__ rank_src, int* __restrict__ rank_dst, int E) {
  const int N = 256, K = 512;
  __shared__ short As[64 * 64];
  __shared__ short Bs[2 * 64 * 64];
  int bid = (int)blockIdx.x;
  long long lo = (long long)bid * nEdge / nTot;
  long long hi = (long long)(bid + 1) * nEdge / nTot;
  if (hi > lo) {
    // --- edge_exp block: eid = lo, 2 edges/thread ---
    int eid = (int)lo;
    int base = eid * 1024;
    int e0 = base + threadIdx.x;
    int e1 = e0 + 512;
    bool v0ok = e0 < E, v1ok = e1 < E;
    float g0 = v0ok ? gate[e0] : 0.f;
    float g1 = v1ok ? gate[e1] : 0.f;
    int s0 = 0, d0 = 0, s1 = 0, d1 = 0;
    if (v0ok) { s0 = idx[2 * e0]; d0 = idx[2 * e0 + 1]; }
    if (v1ok) { s1 = idx[2 * e1]; d1 = idx[2 * e1 + 1]; }
    float v0 = expf(g0 - M_SHIFT);
    float v1 = expf(g1 - M_SHIFT);
    unsigned long long oldc0 = 0, oldc1 = 0;
    int oldd0 = 0, oldd1 = 0;
    if (v0ok) {
      unsigned long long fx = (unsigned long long)((double)v0 * RS_SCALE);
      oldc0 = atomicAdd(&combined[s0], (1ULL << 49) | fx);
      oldd0 = atomicAdd(&deg_dst[d0], 1);
    }
    if (v1ok) {
      unsigned long long fx = (unsigned long long)((double)v1 * RS_SCALE);
      oldc1 = atomicAdd(&combined[s1], (1ULL << 49) | fx);
      oldd1 = atomicAdd(&deg_dst[d1], 1);
    }
    if (v0ok) {
      exp_e[e0] = v0;
      rank_src[e0] = (int)(oldc0 >> 49);
      rank_dst[e0] = oldd0;
    }
    if (v1ok) {
      exp_e[e1] = v1;
      rank_src[e1] = (int)(oldc1 >> 49);
      rank_dst[e1] = oldd1;
    }
    return;
  }
  // --- GEMM1 block: gid = bid - lo (number of edge blocks before bid) ---
  int blk = bid - (int)lo;
  int tid = threadIdx.x;
  int lane = tid & 63, wid = tid >> 6;
  int wm = wid >> 2, wn = wid & 3;
  int m0 = (blk >> 1) * 64;
  int n0 = (blk & 1) * 128;

  f32x4 acc[2][2];
#pragma unroll
  for (int m = 0; m < 2; ++m)
#pragma unroll
    for (int n = 0; n < 2; ++n) acc[m][n] = (f32x4){0.f, 0.f, 0.f, 0.f};

  int ar = tid >> 3, ag = tid & 7;
  bool arow_ok = (m0 + ar) < M;

  for (int k0 = 0; k0 < K; k0 += 64) {
    {
      const float4* ap =
          (const float4*)(Av + (size_t)(m0 + ar) * K + k0 + ag * 8);
      float4 u = make_float4(0.f, 0.f, 0.f, 0.f);
      float4 v = make_float4(0.f, 0.f, 0.f, 0.f);
      if (arow_ok) { u = ap[0]; v = ap[1]; }
      short8 w;
      w[0] = (short)f2bf(u.x); w[1] = (short)f2bf(u.y);
      w[2] = (short)f2bf(u.z); w[3] = (short)f2bf(u.w);
      w[4] = (short)f2bf(v.x); w[5] = (short)f2bf(v.y);
      w[6] = (short)f2bf(v.z); w[7] = (short)f2bf(v.w);
      *(short8*)&As[ar * 64 + ((ag ^ (ar & 7)) << 3)] = w;
    }
#pragma unroll
    for (int nt = 0; nt < 2; ++nt) {
      int r = nt * 64 + ar;
      const short8* bp = (const short8*)(Bt + (size_t)(n0 + r) * K + k0);
      short8 w = bp[ag];
      *(short8*)&Bs[r * 64 + ((ag ^ (r & 7)) << 3)] = w;
    }
    __syncthreads();
    int lsw = lane & 7, l15 = lane & 15, lk = lane >> 4;
#pragma unroll
    for (int kk = 0; kk < 2; ++kk) {
      int gg = kk * 4 + lk;
      int xo = ((gg ^ lsw) << 3);
      short8 af[2];
#pragma unroll
      for (int m = 0; m < 2; ++m)
        af[m] = *(const short8*)&As[(wm * 32 + m * 16 + l15) * 64 + xo];
#pragma unroll
      for (int f = 0; f < 2; ++f) {
        short8 bfr =
            *(const short8*)&Bs[(wn * 32 + f * 16 + l15) * 64 + xo];
#pragma unroll
        for (int m = 0; m < 2; ++m)
          acc[m][f] = __builtin_amdgcn_mfma_f32_16x16x32_bf16(af[m], bfr,
                                                              acc[m][f], 0, 0, 0);
      }
    }
    __syncthreads();
  }
#pragma unroll
  for (int m = 0; m < 2; ++m) {
    int gmBase = m0 + wm * 32 + m * 16 + (lane >> 4) * 4;
#pragma unroll
    for (int f = 0; f < 2; ++f) {
      int gn = n0 + wn * 32 + f * 16 + (lane & 15);
      float bv = bias[gn];
#pragma unroll
      for (int r = 0; r < 4; ++r) {
        int gm = gmBase + r;
        if (gm >= M) continue;
        Cv[(size_t)gm * N + gn] = f2bf(acc[m][f][r] + bv);
      }
    }
  }
}

// Phase 1: decode combined -> (deg_src, row_sum); per-block exclusive scan.
__global__ __launch_bounds__(1024) void scan_part_kernel(
    const unsigned long long* __restrict__ combined,
    const int* __restrict__ degB, float* __restrict__ row_sum,
    int* __restrict__ offA, int* __restrict__ offB, int* __restrict__ sumsA,
    int* __restrict__ sumsB, int n) {
  __shared__ int tA[1024], tB[1024];
  int b = blockIdx.x, t = threadIdx.x;
  int i = b * 1024 + t;
  int vA = 0, vB = 0;
  if (i < n) {
    unsigned long long c = combined[i];
    vA = (int)(c >> 49);
    row_sum[i] = (float)((double)(c & RS_MASK) * (1.0 / RS_SCALE));
    vB = degB[i];
  }
  tA[t] = vA;
  tB[t] = vB;
  __syncthreads();
  for (int off = 1; off < 1024; off <<= 1) {
    int xA = (t >= off) ? tA[t - off] : 0;
    int xB = (t >= off) ? tB[t - off] : 0;
    __syncthreads();
    tA[t] += xA;
    tB[t] += xB;
    __syncthreads();
  }
  if (i < n) {
    offA[i] = tA[t] - vA;  // block-local exclusive
    offB[i] = tB[t] - vB;
  }
  if (t == 1023) {
    sumsA[b] = tA[t];
    sumsB[b] = tB[t];
  }
}

// Phase 2: add carry of preceding blocks.
__global__ __launch_bounds__(1024) void scan_fixup_kernel(
    int* __restrict__ offA, int* __restrict__ offB,
    const int* __restrict__ sumsA, const int* __restrict__ sumsB, int n,
    int nb) {
  __shared__ int cA, cB;
  int b = blockIdx.x, t = threadIdx.x;
  if (t == 0) {
    int ca = 0, cb = 0;
    for (int j = 0; j < b; ++j) {
      ca += sumsA[j];
      cb += sumsB[j];
    }
    cA = ca;
    cB = cb;
  }
  __syncthreads();
  int i = b * 1024 + t;
  if (i < n) {
    offA[i] += cA;
    offB[i] += cB;
  }
  if (b == nb - 1 && t == 0) {
    offA[n] = cA + sumsA[b];
    offB[n] = cB + sumsB[b];
  }
}

// Scatter edges into both CSR lists via precomputed ranks — NO atomics.
// 2 edges/thread.
__global__ void scatter_ids_kernel(const int* __restrict__ idx,
                                   const float* __restrict__ exp_e,
                                   const float* __restrict__ row_sum,
                                   const int* __restrict__ off_src,
                                   const int* __restrict__ off_dst,
                                   const int* __restrict__ rank_src,
                                   const int* __restrict__ rank_dst,
                                   int* __restrict__ oth_src,
                                   float* __restrict__ att_src,
                                   int* __restrict__ oth_dst,
                                   float* __restrict__ att_dst, int E) {
  int base = blockIdx.x * 512;
  int e0 = base + threadIdx.x;
  int e1 = e0 + 256;
#pragma unroll
  for (int k = 0; k < 2; ++k) {
    int e = k ? e1 : e0;
    if (e >= E) continue;
    int s = idx[2 * e], d = idx[2 * e + 1];
    float a = exp_e[e] / (row_sum[s] + 1e-6f);
    int p = off_src[s] + rank_src[e];
    oth_src[p] = d;
    att_src[p] = a;
    int q = off_dst[d] + rank_dst[e];
    oth_dst[q] = s;
    att_dst[q] = a;
  }
}

// One wave per (node, direction); unroll ladder 8/4/2/1 keeps >=2 gathers
// in flight through the tail (mean degree 10).
__global__ __launch_bounds__(256) void aggregate_kernel(
    const int* __restrict__ off_src, const int* __restrict__ oth_src,
    const float* __restrict__ att_src, const int* __restrict__ off_dst,
    const int* __restrict__ oth_dst, const float* __restrict__ att_dst,
    const unsigned short* __restrict__ Mfeat, unsigned short* __restrict__ msg,
    int Nn) {
  int slot = blockIdx.x * 4 + (threadIdx.x >> 6);
  int node = slot >> 1, dir = slot & 1;
  if (node >= Nn) return;
  int lane = threadIdx.x & 63;
  const int* offp = dir ? off_dst : off_src;
  const int* othp = dir ? oth_dst : oth_src;
  const float* attp = dir ? att_dst : att_src;
  float ax = 0.f, ay = 0.f, az = 0.f, aw_ = 0.f;
  int b0 = offp[node], e0 = offp[node + 1];
  for (int base = b0; base < e0; base += 64) {
    int cnt = min(64, e0 - base);
    int oth = (lane < cnt) ? othp[base + lane] : 0;
    float wv = (lane < cnt) ? attp[base + lane] : 0.0f;
    int t = 0;
    for (; t + 8 <= cnt; t += 8) {
      int r0 = __shfl(oth, t, 64), r1 = __shfl(oth, t + 1, 64);
      int r2 = __shfl(oth, t + 2, 64), r3 = __shfl(oth, t + 3, 64);
      int r4 = __shfl(oth, t + 4, 64), r5 = __shfl(oth, t + 5, 64);
      int r6 = __shfl(oth, t + 6, 64), r7 = __shfl(oth, t + 7, 64);
      float w0 = __shfl(wv, t, 64), w1 = __shfl(wv, t + 1, 64);
      float w2 = __shfl(wv, t + 2, 64), w3 = __shfl(wv, t + 3, 64);
      float w4 = __shfl(wv, t + 4, 64), w5 = __shfl(wv, t + 5, 64);
      float w6 = __shfl(wv, t + 6, 64), w7 = __shfl(wv, t + 7, 64);
      ushort4 m0 = *((const ushort4*)(Mfeat + (size_t)r0 * 256) + lane);
      ushort4 m1 = *((const ushort4*)(Mfeat + (size_t)r1 * 256) + lane);
      ushort4 m2 = *((const ushort4*)(Mfeat + (size_t)r2 * 256) + lane);
      ushort4 m3 = *((const ushort4*)(Mfeat + (size_t)r3 * 256) + lane);
      ushort4 m4 = *((const ushort4*)(Mfeat + (size_t)r4 * 256) + lane);
      ushort4 m5 = *((const ushort4*)(Mfeat + (size_t)r5 * 256) + lane);
      ushort4 m6 = *((const ushort4*)(Mfeat + (size_t)r6 * 256) + lane);
      ushort4 m7 = *((const ushort4*)(Mfeat + (size_t)r7 * 256) + lane);
      ax = fmaf(w0, bf2f(m0.x), ax); ay = fmaf(w0, bf2f(m0.y), ay);
      az = fmaf(w0, bf2f(m0.z), az); aw_ = fmaf(w0, bf2f(m0.w), aw_);
      ax = fmaf(w1, bf2f(m1.x), ax); ay = fmaf(w1, bf2f(m1.y), ay);
      az = fmaf(w1, bf2f(m1.z), az); aw_ = fmaf(w1, bf2f(m1.w), aw_);
      ax = fmaf(w2, bf2f(m2.x), ax); ay = fmaf(w2, bf2f(m2.y), ay);
      az = fmaf(w2, bf2f(m2.z), az); aw_ = fmaf(w2, bf2f(m2.w), aw_);
      ax = fmaf(w3, bf2f(m3.x), ax); ay = fmaf(w3, bf2f(m3.y), ay);
      az = fmaf(w3, bf2f(m3.z), az); aw_ = fmaf(w3, bf2f(m3.w), aw_);
      ax = fmaf(w4, bf2f(m4.x), ax); ay = fmaf(w4, bf2f(m4.y), ay);
      az = fmaf(w4, bf2f(m4.z), az); aw_ = fmaf(w4, bf2f(m4.w), aw_);
      ax = fmaf(w5, bf2f(m5.x), ax); ay = fmaf(w5, bf2f(m5.y), ay);
      az = fmaf(w5, bf2f(m5.z), az); aw_ = fmaf(w5, bf2f(m5.w), aw_);
      ax = fmaf(w6, bf2f(m6.x), ax); ay = fmaf(w6, bf2f(m6.y), ay);
      az = fmaf(w6, bf2f(m6.z), az); aw_ = fmaf(w6, bf2f(m6.w), aw_);
      ax = fmaf(w7, bf2f(m7.x), ax); ay = fmaf(w7, bf2f(m7.y), ay);
      az = fmaf(w7, bf2f(m7.z), az); aw_ = fmaf(w7, bf2f(m7.w), aw_);
    }
    for (; t + 4 <= cnt; t += 4) {
      int r0 = __shfl(oth, t, 64), r1 = __shfl(oth, t + 1, 64);
      int r2 = __shfl(oth, t + 2, 64), r3 = __shfl(oth, t + 3, 64);
      float w0 = __shfl(wv, t, 64), w1 = __shfl(wv, t + 1, 64);
      float w2 = __shfl(wv, t + 2, 64), w3 = __shfl(wv, t + 3, 64);
      ushort4 m0 = *((const ushort4*)(Mfeat + (size_t)r0 * 256) + lane);
      ushort4 m1 = *((const ushort4*)(Mfeat + (size_t)r1 * 256) + lane);
      ushort4 m2 = *((const ushort4*)(Mfeat + (size_t)r2 * 256) + lane);
      ushort4 m3 = *((const ushort4*)(Mfeat + (size_t)r3 * 256) + lane);
      ax = fmaf(w0, bf2f(m0.x), ax); ay = fmaf(w0, bf2f(m0.y), ay);
      az = fmaf(w0, bf2f(m0.z), az); aw_ = fmaf(w0, bf2f(m0.w), aw_);
      ax = fmaf(w1, bf2f(m1.x), ax); ay = fmaf(w1, bf2f(m1.y), ay);
      az = fmaf(w1, bf2f(m1.z), az); aw_ = fmaf(w1, bf2f(m1.w), aw_);
      ax = fmaf(w2, bf2f(m2.x), ax); ay = fmaf(w2, bf2f(m2.y), ay);
      az = fmaf(w2, bf2f(m2.z), az); aw_ = fmaf(w2, bf2f(m2.w), aw_);
      ax = fmaf(w3, bf2f(m3.x), ax); ay = fmaf(w3, bf2f(m3.y), ay);
      az = fmaf(w3, bf2f(m3.z), az); aw_ = fmaf(w3, bf2f(m3.w), aw_);
    }
    for (; t + 2 <= cnt; t += 2) {
      int r0 = __shfl(oth, t, 64), r1 = __shfl(oth, t + 1, 64);
      float w0 = __shfl(wv, t, 64), w1 = __shfl(wv, t + 1, 64);
      ushort4 m0 = *((const ushort4*)(Mfeat + (size_t)r0 * 256) + lane);
      ushort4 m1 = *((const ushort4*)(Mfeat + (size_t)r1 * 256) + lane);
      ax = fmaf(w0, bf2f(m0.x), ax); ay = fmaf(w0, bf2f(m0.y), ay);
      az = fmaf(w0, bf2f(m0.z), az); aw_ = fmaf(w0, bf2f(m0.w), aw_);
      ax = fmaf(w1, bf2f(m1.x), ax); ay = fmaf(w1, bf2f(m1.y), ay);
      az = fmaf(w1, bf2f(m1.z), az); aw_ = fmaf(w1, bf2f(m1.w), aw_);
    }
    for (; t < cnt; ++t) {
      int r = __shfl(oth, t, 64);
      float w = __shfl(wv, t, 64);
      ushort4 mv = *((const ushort4*)(Mfeat + (size_t)r * 256) + lane);
      ax = fmaf(w, bf2f(mv.x), ax); ay = fmaf(w, bf2f(mv.y), ay);
      az = fmaf(w, bf2f(mv.z), az); aw_ = fmaf(w, bf2f(mv.w), aw_);
    }
  }
  ushort4 o;
  o.x = f2bf(ax); o.y = f2bf(ay); o.z = f2bf(az); o.w = f2bf(aw_);
  *((ushort4*)(msg + (size_t)node * 512 + dir * 256) + lane) = o;
}

// bf16 MFMA GEMM: C[M,N] = A[M,K] @ Bt[N,K]^T + bias. (GEMM3)
template <int ABF16, int OUT_MODE, int NT>
__global__ __launch_bounds__(512) void mfma_gemm_kernel(
    const void* __restrict__ Av, const short* __restrict__ Bt,
    const float* __restrict__ bias, const float* __restrict__ row_sum,
    void* __restrict__ Cv, int M, int N, int K) {
  __shared__ short As[64 * 64];
  __shared__ short Bs[NT * 64 * 64];
  int tid = threadIdx.x;
  int lane = tid & 63, wid = tid >> 6;  // 8 waves
  int wm = wid >> 2, wn = wid & 3;      // 2 x 4
  int m0 = blockIdx.x * 64, n0 = blockIdx.y * (64 * NT);

  f32x4 acc[2][NT];
#pragma unroll
  for (int m = 0; m < 2; ++m)
#pragma unroll
    for (int n = 0; n < NT; ++n) acc[m][n] = (f32x4){0.f, 0.f, 0.f, 0.f};

  int ar = tid >> 3;
  int ag = tid & 7;
  bool arow_ok = (m0 + ar) < M;

  for (int k0 = 0; k0 < K; k0 += 64) {
    if (ABF16) {
      const short8* ap =
          (const short8*)((const short*)Av + (size_t)(m0 + ar) * K + k0);
      short8 w = (short8){0, 0, 0, 0, 0, 0, 0, 0};
      if (arow_ok) w = ap[ag];
      *(short8*)&As[ar * 64 + ((ag ^ (ar & 7)) << 3)] = w;
    } else {
      const float4* ap =
          (const float4*)((const float*)Av + (size_t)(m0 + ar) * K + k0 + ag * 8);
      float4 u = make_float4(0.f, 0.f, 0.f, 0.f);
      float4 v = make_float4(0.f, 0.f, 0.f, 0.f);
      if (arow_ok) { u = ap[0]; v = ap[1]; }
      short8 w;
      w[0] = (short)f2bf(u.x); w[1] = (short)f2bf(u.y);
      w[2] = (short)f2bf(u.z); w[3] = (short)f2bf(u.w);
      w[4] = (short)f2bf(v.x); w[5] = (short)f2bf(v.y);
      w[6] = (short)f2bf(v.z); w[7] = (short)f2bf(v.w);
      *(short8*)&As[ar * 64 + ((ag ^ (ar & 7)) << 3)] = w;
    }
#pragma unroll
    for (int nt = 0; nt < NT; ++nt) {
      int r = nt * 64 + ar;
      const short8* bp = (const short8*)(Bt + (size_t)(n0 + r) * K + k0);
      short8 w = bp[ag];
      *(short8*)&Bs[r * 64 + ((ag ^ (r & 7)) << 3)] = w;
    }
    __syncthreads();
    int lsw = lane & 7, l15 = lane & 15, lk = lane >> 4;
#pragma unroll
    for (int kk = 0; kk < 2; ++kk) {
      int gg = kk * 4 + lk;
      int xo = ((gg ^ lsw) << 3);
      short8 af[2];
#pragma unroll
      for (int m = 0; m < 2; ++m)
        af[m] = *(const short8*)&As[(wm * 32 + m * 16 + l15) * 64 + xo];
#pragma unroll
      for (int f = 0; f < NT; ++f) {
        short8 bfr =
            *(const short8*)&Bs[(wn * NT * 16 + f * 16 + l15) * 64 + xo];
#pragma unroll
        for (int m = 0; m < 2; ++m)
          acc[m][f] = __builtin_amdgcn_mfma_f32_16x16x32_bf16(af[m], bfr,
                                                              acc[m][f], 0, 0, 0);
      }
    }
    __syncthreads();
  }
#pragma unroll
  for (int m = 0; m < 2; ++m) {
    int gmBase = m0 + wm * 32 + m * 16 + (lane >> 4) * 4;
#pragma unroll
    for (int f = 0; f < NT; ++f) {
      int gn = n0 + wn * NT * 16 + f * 16 + (lane & 15);
      float bv = bias[gn];
#pragma unroll
      for (int r = 0; r < 4; ++r) {
        int gm = gmBase + r;
        if (gm >= M) continue;
        float v = acc[m][f][r] + bv;
        if (OUT_MODE == 1) v = (row_sum[gm] > 0.0f) ? fmaxf(v, 0.0f) : 0.0f;
        if (OUT_MODE == 2)
          ((unsigned short*)Cv)[(size_t)gm * N + gn] = f2bf(v);
        else
          ((float*)Cv)[(size_t)gm * N + gn] = v;
      }
    }
  }
}

// GEMM2 fused with LayerNorm+ReLU: h1ln(bf16) = relu(LN(msg @ W1 + b1)).
__global__ __launch_bounds__(512) void gemm2_ln_kernel(
    const unsigned short* __restrict__ msg, const short* __restrict__ W1T,
    const float* __restrict__ b1, const float* __restrict__ gamma,
    const float* __restrict__ beta, unsigned short* __restrict__ h1ln,
    int M) {
  __shared__ short As[64 * 64];
  __shared__ short Bs[128 * 64];
  __shared__ float lnS[64][4];
  __shared__ float lnQ[64][4];
  const int K = 512;
  int tid = threadIdx.x;
  int lane = tid & 63, wid = tid >> 6;  // 8 waves
  int wm = wid >> 2, wn = wid & 3;      // 2m x 4n (4n x 32 cols = 128)
  int m0 = blockIdx.x * 64;

  f32x4 acc[2][2];
#pragma unroll
  for (int m = 0; m < 2; ++m)
#pragma unroll
    for (int n = 0; n < 2; ++n) acc[m][n] = (f32x4){0.f, 0.f, 0.f, 0.f};

  int ar = tid >> 3, ag = tid & 7;
  bool arow_ok = (m0 + ar) < M;
  int br = tid >> 2;       // B row 0..127
  int bg = (tid & 3) * 2;  // 2 k-groups each

  for (int k0 = 0; k0 < K; k0 += 64) {
    {
      const short8* ap =
          (const short8*)((const short*)msg + (size_t)(m0 + ar) * K + k0);
      short8 w = (short8){0, 0, 0, 0, 0, 0, 0, 0};
      if (arow_ok) w = ap[ag];
      *(short8*)&As[ar * 64 + ((ag ^ (ar & 7)) << 3)] = w;
    }
    {
      const short8* bp = (const short8*)(W1T + (size_t)br * K + k0);
#pragma unroll
      for (int g2 = 0; g2 < 2; ++g2) {
        int g = bg + g2;
        short8 w = bp[g];
        *(short8*)&Bs[br * 64 + ((g ^ (br & 7)) << 3)] = w;
      }
    }
    __syncthreads();
    int lsw = lane & 7, l15 = lane & 15, lk = lane >> 4;
#pragma unroll
    for (int kk = 0; kk < 2; ++kk) {
      int gg = kk * 4 + lk;
      int xo = ((gg ^ lsw) << 3);
      short8 af[2];
#pragma unroll
      for (int m = 0; m < 2; ++m)
        af[m] = *(const short8*)&As[(wm * 32 + m * 16 + l15) * 64 + xo];
#pragma unroll
      for (int n = 0; n < 2; ++n) {
        short8 bfr = *(const short8*)&Bs[(wn * 32 + n * 16 + l15) * 64 + xo];
#pragma unroll
        for (int m = 0; m < 2; ++m)
          acc[m][n] = __builtin_amdgcn_mfma_f32_16x16x32_bf16(af[m], bfr,
                                                              acc[m][n], 0, 0, 0);
      }
    }
    __syncthreads();
  }

  // --- LN epilogue ---
  int l15 = lane & 15, lg = lane >> 4;
  int c0 = wn * 32 + l15, c1 = c0 + 16;
  float bv0 = b1[c0], bv1 = b1[c1];
  float g0 = gamma[c0], g1 = gamma[c1];
  float be0 = beta[c0], be1 = beta[c1];
#pragma unroll
  for (int m = 0; m < 2; ++m) {
#pragma unroll
    for (int r = 0; r < 4; ++r) {
      float v0 = acc[m][0][r] + bv0, v1 = acc[m][1][r] + bv1;
      float s1 = v0 + v1;
      float s2 = v0 * v0 + v1 * v1;
#pragma unroll
      for (int mk = 1; mk < 16; mk <<= 1) {
        s1 += __shfl_xor(s1, mk, 64);
        s2 += __shfl_xor(s2, mk, 64);
      }
      int row_l = wm * 32 + m * 16 + lg * 4 + r;
      if (l15 == 0) {
        lnS[row_l][wn] = s1;
        lnQ[row_l][wn] = s2;
      }
    }
  }
  __syncthreads();
#pragma unroll
  for (int m = 0; m < 2; ++m) {
#pragma unroll
    for (int r = 0; r < 4; ++r) {
      int row_l = wm * 32 + m * 16 + lg * 4 + r;
      int gm = m0 + row_l;
      if (gm >= M) continue;
      float S = lnS[row_l][0] + lnS[row_l][1] + lnS[row_l][2] + lnS[row_l][3];
      float Q = lnQ[row_l][0] + lnQ[row_l][1] + lnQ[row_l][2] + lnQ[row_l][3];
      float mu = S * 0.0078125f;             // /128
      float var = Q * 0.0078125f - mu * mu;  // E[x^2]-mu^2
      float rs = rsqrtf(var + 1e-5f);
      float v0 = acc[m][0][r] + bv0, v1 = acc[m][1][r] + bv1;
      float y0 = fmaxf((v0 - mu) * rs * g0 + be0, 0.0f);
      float y1 = fmaxf((v1 - mu) * rs * g1 + be1, 0.0f);
      h1ln[(size_t)gm * 128 + c0] = f2bf(y0);
      h1ln[(size_t)gm * 128 + c1] = f2bf(y1);
    }
  }
}

extern "C" void kernel_launch(void* const* d_in, const int* in_sizes, int n_in,
                              void* d_out, int out_size, void* d_ws,
                              size_t ws_size, hipStream_t stream) {
  const float* src_feat = (const float*)d_in[0];
  const float* gate = (const float*)d_in[1];
  const int* idx = (const int*)d_in[2];
  const float* Wm = (const float*)d_in[3];
  const float* bm = (const float*)d_in[4];
  const float* W1 = (const float*)d_in[5];
  const float* b1 = (const float*)d_in[6];
  const float* gamma = (const float*)d_in[7];
  const float* beta = (const float*)d_in[8];
  const float* W2 = (const float*)d_in[9];
  const float* b2 = (const float*)d_in[10];
  float* out = (float*)d_out;

  const int D = 512;
  const int Nn = in_sizes[0] / D;  // 20000
  const int E = in_sizes[1];       // 200000

  char* ws = (char*)d_ws;
  size_t off = 0;
  auto alloc = [&](size_t bytes) {
    void* p = ws + off;
    off = (off + bytes + 255) & ~(size_t)255;
    return p;
  };
  // zero-region: combined (u64) + deg_dst (contiguous)
  unsigned long long* combined = (unsigned long long*)alloc((size_t)Nn * 8);
  int* deg_dst = (int*)alloc((size_t)Nn * 4);
  char* z_end = ws + off;
  float* row_sum = (float*)alloc((size_t)Nn * 4);  // written by scan_part
  float* exp_e = (float*)alloc((size_t)E * 4);
  int* rank_src = (int*)alloc((size_t)E * 4);
  int* rank_dst = (int*)alloc((size_t)E * 4);
  unsigned short* Mfeat = (unsigned short*)alloc((size_t)Nn * 256 * 2);
  unsigned short* msg = (unsigned short*)alloc((size_t)Nn * 512 * 2);
  unsigned short* h1ln = (unsigned short*)alloc((size_t)Nn * 128 * 2);
  short* WmT = (short*)alloc((size_t)512 * 256 * 2);
  short* W1T = (short*)alloc((size_t)512 * 128 * 2);
  short* W2T = (short*)alloc((size_t)128 * 512 * 2);
  int* off_src = (int*)alloc((size_t)(Nn + 1) * 4);
  int* off_dst = (int*)alloc((size_t)(Nn + 1) * 4);
  int* oth_src = (int*)alloc((size_t)E * 4);
  float* att_src = (float*)alloc((size_t)E * 4);
  int* oth_dst = (int*)alloc((size_t)E * 4);
  float* att_dst = (float*)alloc((size_t)E * 4);
  int* sumsA = (int*)alloc(64 * 4);
  int* sumsB = (int*)alloc(64 * 4);

  int n1 = (int)((z_end - (char*)combined) >> 2);
  init_kernel<<<1024, 256, 0, stream>>>((unsigned int*)combined, n1, Wm, WmT,
                                        W1, W1T, W2, W2T);

  int gx = (Nn + 63) / 64;            // 313
  int gemmBlocks = gx * 2;            // 626 (NT=2, 2 n-tiles)
  int edgeBlocks = (E + 1023) / 1024; // 196 (2 edges/thread)
  int totBlocks = gemmBlocks + edgeBlocks;  // 822
  // Role-interleaved fused launch: edge and GEMM blocks Bresenham-mixed
  gemm1_edge_kernel<<<totBlocks, 512, 0, stream>>>(
      src_feat, WmT, bm, Mfeat, Nn, edgeBlocks, totBlocks, gate, idx, exp_e,
      combined, deg_dst, rank_src, rank_dst, E);

  int nb = (Nn + 1023) / 1024;  // 20
  scan_part_kernel<<<nb, 1024, 0, stream>>>(combined, deg_dst, row_sum,
                                            off_src, off_dst, sumsA, sumsB,
                                            Nn);
  scan_fixup_kernel<<<nb, 1024, 0, stream>>>(off_src, off_dst, sumsA, sumsB,
                                             Nn, nb);
  // scatter: NO atomics (rank-based slots), 2 edges/thread
  scatter_ids_kernel<<<(E + 511) / 512, 256, 0, stream>>>(
      idx, exp_e, row_sum, off_src, off_dst, rank_src, rank_dst, oth_src,
      att_src, oth_dst, att_dst, E);
  // aggregate: one wave per (node, dir) -> 40000 waves
  aggregate_kernel<<<(2 * Nn + 3) / 4, 256, 0, stream>>>(
      off_src, oth_src, att_src, off_dst, oth_dst, att_dst, Mfeat, msg, Nn);
  // GEMM2 + LN + ReLU fused: h1ln(bf16) = relu(LN(msg @ W1 + b1))
  gemm2_ln_kernel<<<gx, 512, 0, stream>>>(msg, W1T, b1, gamma, beta, h1ln, Nn);
  // GEMM3: out(f32) = h1ln(bf16) @ W2 + b2, relu+mask  [M=Nn,N=512,K=128],
  //        NT=4, y=2
  mfma_gemm_kernel<1, 1, 4><<<dim3(gx, 2), 512, 0, stream>>>(
      h1ln, W2T, b2, row_sum, out, Nn, 512, 128);
}

// Round 25
// 110.700 us; speedup vs baseline: 1.0575x; 1.0179x over previous
//
#include <hip/hip_runtime.h>
#include <math.h>

// ---------------------------------------------------------------------------
// MessageGenerator: edge-softmax attention message passing + MLP head.
// N=20000 nodes, E=200000 edges, D=512, Dm=256, Dh=128, H=512.
// R1-R23: see history. R23 = 112.7us (best): Bresenham role-interleave of
// edge/GEMM blocks confirmed co-scheduling mechanism (-3.9us).
// R24: (1) finer interleave (1 edge/thread -> 391 edge blocks, ~1:1.6 mix);
//      (2) (oth,att) packed as int2 -> one 8B load per CSR slot in
//      aggregate's latency-critical metadata phase.
// ---------------------------------------------------------------------------

typedef __attribute__((ext_vector_type(8))) short short8;
typedef __attribute__((ext_vector_type(4))) float f32x4;

#define M_SHIFT 4.75f  // const softmax shift; only couples via +1e-6 eps
#define RS_SCALE 1099511627776.0  // 2^40
#define RS_MASK ((1ULL << 49) - 1)

static __device__ __forceinline__ unsigned short f2bf(float f) {
  union { float f; unsigned int u; } v; v.f = f;
  unsigned int r = v.u + 0x7fffu + ((v.u >> 16) & 1u);  // round-nearest-even
  return (unsigned short)(r >> 16);
}
static __device__ __forceinline__ float bf2f(unsigned short b) {
  union { unsigned int u; float f; } v; v.u = ((unsigned int)b) << 16;
  return v.f;
}

// Zero one dword region + transpose/convert all three weights. One launch.
__global__ void init_kernel(unsigned int* __restrict__ z1, int n1,
                            const float* __restrict__ Wm,
                            short* __restrict__ WmT,
                            const float* __restrict__ W1,
                            short* __restrict__ W1T,
                            const float* __restrict__ W2,
                            short* __restrict__ W2T) {
  int i = blockIdx.x * 256 + threadIdx.x;
  int stride = gridDim.x * 256;
  for (int j = i; j < n1; j += stride) z1[j] = 0u;
  if (i < 131072) {
    int n = i >> 9, k = i & 511;  // K=512, N=256
    WmT[i] = (short)f2bf(Wm[(size_t)k * 256 + n]);
  } else if (i < 196608) {
    int j = i - 131072;
    int n = j >> 9, k = j & 511;  // K=512, N=128
    W1T[j] = (short)f2bf(W1[(size_t)k * 128 + n]);
  } else if (i < 262144) {
    int j = i - 196608;
    int n = j >> 7, k = j & 127;  // K=128, N=512
    W2T[j] = (short)f2bf(W2[(size_t)k * 512 + n]);
  }
}

// Fused, role-INTERLEAVED (Bresenham): block bid is an edge block iff
// floor((bid+1)*nEdge/nTot) > floor(bid*nEdge/nTot). 1 edge/thread.
__global__ __launch_bounds__(512) void gemm1_edge_kernel(
    const float* __restrict__ Av, const short* __restrict__ Bt,
    const float* __restrict__ bias, unsigned short* __restrict__ Cv, int M,
    int nEdge, int nTot, const float* __restrict__ gate,
    const int* __restrict__ idx, float* __restrict__ exp_e,
    unsigned long long* __restrict__ combined, int* __restrict__ deg_dst,
    int* __restrict__ rank_src, int* __restrict__ rank_dst, int E) {
  const int N = 256, K = 512;
  __shared__ short As[64 * 64];
  __shared__ short Bs[2 * 64 * 64];
  int bid = (int)blockIdx.x;
  long long lo = (long long)bid * nEdge / nTot;
  long long hi = (long long)(bid + 1) * nEdge / nTot;
  if (hi > lo) {
    // --- edge_exp block: eid = lo, 1 edge/thread ---
    int e = (int)lo * 512 + threadIdx.x;
    if (e < E) {
      float v = expf(gate[e] - M_SHIFT);
      exp_e[e] = v;
      int s = idx[2 * e], d = idx[2 * e + 1];
      unsigned long long fx = (unsigned long long)((double)v * RS_SCALE);
      unsigned long long oldc = atomicAdd(&combined[s], (1ULL << 49) | fx);
      int oldd = atomicAdd(&deg_dst[d], 1);
      rank_src[e] = (int)(oldc >> 49);
      rank_dst[e] = oldd;
    }
    return;
  }
  // --- GEMM1 block: gid = bid - lo ---
  int blk = bid - (int)lo;
  int tid = threadIdx.x;
  int lane = tid & 63, wid = tid >> 6;
  int wm = wid >> 2, wn = wid & 3;
  int m0 = (blk >> 1) * 64;
  int n0 = (blk & 1) * 128;

  f32x4 acc[2][2];
#pragma unroll
  for (int m = 0; m < 2; ++m)
#pragma unroll
    for (int n = 0; n < 2; ++n) acc[m][n] = (f32x4){0.f, 0.f, 0.f, 0.f};

  int ar = tid >> 3, ag = tid & 7;
  bool arow_ok = (m0 + ar) < M;

  for (int k0 = 0; k0 < K; k0 += 64) {
    {
      const float4* ap =
          (const float4*)(Av + (size_t)(m0 + ar) * K + k0 + ag * 8);
      float4 u = make_float4(0.f, 0.f, 0.f, 0.f);
      float4 v = make_float4(0.f, 0.f, 0.f, 0.f);
      if (arow_ok) { u = ap[0]; v = ap[1]; }
      short8 w;
      w[0] = (short)f2bf(u.x); w[1] = (short)f2bf(u.y);
      w[2] = (short)f2bf(u.z); w[3] = (short)f2bf(u.w);
      w[4] = (short)f2bf(v.x); w[5] = (short)f2bf(v.y);
      w[6] = (short)f2bf(v.z); w[7] = (short)f2bf(v.w);
      *(short8*)&As[ar * 64 + ((ag ^ (ar & 7)) << 3)] = w;
    }
#pragma unroll
    for (int nt = 0; nt < 2; ++nt) {
      int r = nt * 64 + ar;
      const short8* bp = (const short8*)(Bt + (size_t)(n0 + r) * K + k0);
      short8 w = bp[ag];
      *(short8*)&Bs[r * 64 + ((ag ^ (r & 7)) << 3)] = w;
    }
    __syncthreads();
    int lsw = lane & 7, l15 = lane & 15, lk = lane >> 4;
#pragma unroll
    for (int kk = 0; kk < 2; ++kk) {
      int gg = kk * 4 + lk;
      int xo = ((gg ^ lsw) << 3);
      short8 af[2];
#pragma unroll
      for (int m = 0; m < 2; ++m)
        af[m] = *(const short8*)&As[(wm * 32 + m * 16 + l15) * 64 + xo];
#pragma unroll
      for (int f = 0; f < 2; ++f) {
        short8 bfr =
            *(const short8*)&Bs[(wn * 32 + f * 16 + l15) * 64 + xo];
#pragma unroll
        for (int m = 0; m < 2; ++m)
          acc[m][f] = __builtin_amdgcn_mfma_f32_16x16x32_bf16(af[m], bfr,
                                                              acc[m][f], 0, 0, 0);
      }
    }
    __syncthreads();
  }
#pragma unroll
  for (int m = 0; m < 2; ++m) {
    int gmBase = m0 + wm * 32 + m * 16 + (lane >> 4) * 4;
#pragma unroll
    for (int f = 0; f < 2; ++f) {
      int gn = n0 + wn * 32 + f * 16 + (lane & 15);
      float bv = bias[gn];
#pragma unroll
      for (int r = 0; r < 4; ++r) {
        int gm = gmBase + r;
        if (gm >= M) continue;
        Cv[(size_t)gm * N + gn] = f2bf(acc[m][f][r] + bv);
      }
    }
  }
}

// Phase 1: decode combined -> (deg_src, row_sum); per-block exclusive scan.
__global__ __launch_bounds__(1024) void scan_part_kernel(
    const unsigned long long* __restrict__ combined,
    const int* __restrict__ degB, float* __restrict__ row_sum,
    int* __restrict__ offA, int* __restrict__ offB, int* __restrict__ sumsA,
    int* __restrict__ sumsB, int n) {
  __shared__ int tA[1024], tB[1024];
  int b = blockIdx.x, t = threadIdx.x;
  int i = b * 1024 + t;
  int vA = 0, vB = 0;
  if (i < n) {
    unsigned long long c = combined[i];
    vA = (int)(c >> 49);
    row_sum[i] = (float)((double)(c & RS_MASK) * (1.0 / RS_SCALE));
    vB = degB[i];
  }
  tA[t] = vA;
  tB[t] = vB;
  __syncthreads();
  for (int off = 1; off < 1024; off <<= 1) {
    int xA = (t >= off) ? tA[t - off] : 0;
    int xB = (t >= off) ? tB[t - off] : 0;
    __syncthreads();
    tA[t] += xA;
    tB[t] += xB;
    __syncthreads();
  }
  if (i < n) {
    offA[i] = tA[t] - vA;  // block-local exclusive
    offB[i] = tB[t] - vB;
  }
  if (t == 1023) {
    sumsA[b] = tA[t];
    sumsB[b] = tB[t];
  }
}

// Phase 2: add carry of preceding blocks.
__global__ __launch_bounds__(1024) void scan_fixup_kernel(
    int* __restrict__ offA, int* __restrict__ offB,
    const int* __restrict__ sumsA, const int* __restrict__ sumsB, int n,
    int nb) {
  __shared__ int cA, cB;
  int b = blockIdx.x, t = threadIdx.x;
  if (t == 0) {
    int ca = 0, cb = 0;
    for (int j = 0; j < b; ++j) {
      ca += sumsA[j];
      cb += sumsB[j];
    }
    cA = ca;
    cB = cb;
  }
  __syncthreads();
  int i = b * 1024 + t;
  if (i < n) {
    offA[i] += cA;
    offB[i] += cB;
  }
  if (b == nb - 1 && t == 0) {
    offA[n] = cA + sumsA[b];
    offB[n] = cB + sumsB[b];
  }
}

// Scatter edges into both CSR lists via precomputed ranks — NO atomics.
// (oth, att) packed as one int2 per slot. 2 edges/thread.
__global__ void scatter_ids_kernel(const int* __restrict__ idx,
                                   const float* __restrict__ exp_e,
                                   const float* __restrict__ row_sum,
                                   const int* __restrict__ off_src,
                                   const int* __restrict__ off_dst,
                                   const int* __restrict__ rank_src,
                                   const int* __restrict__ rank_dst,
                                   int2* __restrict__ pair_src,
                                   int2* __restrict__ pair_dst, int E) {
  int base = blockIdx.x * 512;
  int e0 = base + threadIdx.x;
  int e1 = e0 + 256;
#pragma unroll
  for (int k = 0; k < 2; ++k) {
    int e = k ? e1 : e0;
    if (e >= E) continue;
    int s = idx[2 * e], d = idx[2 * e + 1];
    float a = exp_e[e] / (row_sum[s] + 1e-6f);
    int ai = __float_as_int(a);
    pair_src[off_src[s] + rank_src[e]] = make_int2(d, ai);
    pair_dst[off_dst[d] + rank_dst[e]] = make_int2(s, ai);
  }
}

// One wave per (node, direction); unroll ladder 8/4/2/1. Metadata = one
// int2 (oth, att) load per slot.
__global__ __launch_bounds__(256) void aggregate_kernel(
    const int* __restrict__ off_src, const int2* __restrict__ pair_src,
    const int* __restrict__ off_dst, const int2* __restrict__ pair_dst,
    const unsigned short* __restrict__ Mfeat, unsigned short* __restrict__ msg,
    int Nn) {
  int slot = blockIdx.x * 4 + (threadIdx.x >> 6);
  int node = slot >> 1, dir = slot & 1;
  if (node >= Nn) return;
  int lane = threadIdx.x & 63;
  const int* offp = dir ? off_dst : off_src;
  const int2* pp = dir ? pair_dst : pair_src;
  float ax = 0.f, ay = 0.f, az = 0.f, aw_ = 0.f;
  int b0 = offp[node], e0 = offp[node + 1];
  for (int base = b0; base < e0; base += 64) {
    int cnt = min(64, e0 - base);
    int2 pr = (lane < cnt) ? pp[base + lane] : make_int2(0, 0);
    int oth = pr.x;
    float wv = __int_as_float(pr.y);
    if (lane >= cnt) wv = 0.0f;
    int t = 0;
    for (; t + 8 <= cnt; t += 8) {
      int r0 = __shfl(oth, t, 64), r1 = __shfl(oth, t + 1, 64);
      int r2 = __shfl(oth, t + 2, 64), r3 = __shfl(oth, t + 3, 64);
      int r4 = __shfl(oth, t + 4, 64), r5 = __shfl(oth, t + 5, 64);
      int r6 = __shfl(oth, t + 6, 64), r7 = __shfl(oth, t + 7, 64);
      float w0 = __shfl(wv, t, 64), w1 = __shfl(wv, t + 1, 64);
      float w2 = __shfl(wv, t + 2, 64), w3 = __shfl(wv, t + 3, 64);
      float w4 = __shfl(wv, t + 4, 64), w5 = __shfl(wv, t + 5, 64);
      float w6 = __shfl(wv, t + 6, 64), w7 = __shfl(wv, t + 7, 64);
      ushort4 m0 = *((const ushort4*)(Mfeat + (size_t)r0 * 256) + lane);
      ushort4 m1 = *((const ushort4*)(Mfeat + (size_t)r1 * 256) + lane);
      ushort4 m2 = *((const ushort4*)(Mfeat + (size_t)r2 * 256) + lane);
      ushort4 m3 = *((const ushort4*)(Mfeat + (size_t)r3 * 256) + lane);
      ushort4 m4 = *((const ushort4*)(Mfeat + (size_t)r4 * 256) + lane);
      ushort4 m5 = *((const ushort4*)(Mfeat + (size_t)r5 * 256) + lane);
      ushort4 m6 = *((const ushort4*)(Mfeat + (size_t)r6 * 256) + lane);
      ushort4 m7 = *((const ushort4*)(Mfeat + (size_t)r7 * 256) + lane);
      ax = fmaf(w0, bf2f(m0.x), ax); ay = fmaf(w0, bf2f(m0.y), ay);
      az = fmaf(w0, bf2f(m0.z), az); aw_ = fmaf(w0, bf2f(m0.w), aw_);
      ax = fmaf(w1, bf2f(m1.x), ax); ay = fmaf(w1, bf2f(m1.y), ay);
      az = fmaf(w1, bf2f(m1.z), az); aw_ = fmaf(w1, bf2f(m1.w), aw_);
      ax = fmaf(w2, bf2f(m2.x), ax); ay = fmaf(w2, bf2f(m2.y), ay);
      az = fmaf(w2, bf2f(m2.z), az); aw_ = fmaf(w2, bf2f(m2.w), aw_);
      ax = fmaf(w3, bf2f(m3.x), ax); ay = fmaf(w3, bf2f(m3.y), ay);
      az = fmaf(w3, bf2f(m3.z), az); aw_ = fmaf(w3, bf2f(m3.w), aw_);
      ax = fmaf(w4, bf2f(m4.x), ax); ay = fmaf(w4, bf2f(m4.y), ay);
      az = fmaf(w4, bf2f(m4.z), az); aw_ = fmaf(w4, bf2f(m4.w), aw_);
      ax = fmaf(w5, bf2f(m5.x), ax); ay = fmaf(w5, bf2f(m5.y), ay);
      az = fmaf(w5, bf2f(m5.z), az); aw_ = fmaf(w5, bf2f(m5.w), aw_);
      ax = fmaf(w6, bf2f(m6.x), ax); ay = fmaf(w6, bf2f(m6.y), ay);
      az = fmaf(w6, bf2f(m6.z), az); aw_ = fmaf(w6, bf2f(m6.w), aw_);
      ax = fmaf(w7, bf2f(m7.x), ax); ay = fmaf(w7, bf2f(m7.y), ay);
      az = fmaf(w7, bf2f(m7.z), az); aw_ = fmaf(w7, bf2f(m7.w), aw_);
    }
    for (; t + 4 <= cnt; t += 4) {
      int r0 = __shfl(oth, t, 64), r1 = __shfl(oth, t + 1, 64);
      int r2 = __shfl(oth, t + 2, 64), r3 = __shfl(oth, t + 3, 64);
      float w0 = __shfl(wv, t, 64), w1 = __shfl(wv, t + 1, 64);
      float w2 = __shfl(wv, t + 2, 64), w3 = __shfl(wv, t + 3, 64);
      ushort4 m0 = *((const ushort4*)(Mfeat + (size_t)r0 * 256) + lane);
      ushort4 m1 = *((const ushort4*)(Mfeat + (size_t)r1 * 256) + lane);
      ushort4 m2 = *((const ushort4*)(Mfeat + (size_t)r2 * 256) + lane);
      ushort4 m3 = *((const ushort4*)(Mfeat + (size_t)r3 * 256) + lane);
      ax = fmaf(w0, bf2f(m0.x), ax); ay = fmaf(w0, bf2f(m0.y), ay);
      az = fmaf(w0, bf2f(m0.z), az); aw_ = fmaf(w0, bf2f(m0.w), aw_);
      ax = fmaf(w1, bf2f(m1.x), ax); ay = fmaf(w1, bf2f(m1.y), ay);
      az = fmaf(w1, bf2f(m1.z), az); aw_ = fmaf(w1, bf2f(m1.w), aw_);
      ax = fmaf(w2, bf2f(m2.x), ax); ay = fmaf(w2, bf2f(m2.y), ay);
      az = fmaf(w2, bf2f(m2.z), az); aw_ = fmaf(w2, bf2f(m2.w), aw_);
      ax = fmaf(w3, bf2f(m3.x), ax); ay = fmaf(w3, bf2f(m3.y), ay);
      az = fmaf(w3, bf2f(m3.z), az); aw_ = fmaf(w3, bf2f(m3.w), aw_);
    }
    for (; t + 2 <= cnt; t += 2) {
      int r0 = __shfl(oth, t, 64), r1 = __shfl(oth, t + 1, 64);
      float w0 = __shfl(wv, t, 64), w1 = __shfl(wv, t + 1, 64);
      ushort4 m0 = *((const ushort4*)(Mfeat + (size_t)r0 * 256) + lane);
      ushort4 m1 = *((const ushort4*)(Mfeat + (size_t)r1 * 256) + lane);
      ax = fmaf(w0, bf2f(m0.x), ax); ay = fmaf(w0, bf2f(m0.y), ay);
      az = fmaf(w0, bf2f(m0.z), az); aw_ = fmaf(w0, bf2f(m0.w), aw_);
      ax = fmaf(w1, bf2f(m1.x), ax); ay = fmaf(w1, bf2f(m1.y), ay);
      az = fmaf(w1, bf2f(m1.z), az); aw_ = fmaf(w1, bf2f(m1.w), aw_);
    }
    for (; t < cnt; ++t) {
      int r = __shfl(oth, t, 64);
      float w = __shfl(wv, t, 64);
      ushort4 mv = *((const ushort4*)(Mfeat + (size_t)r * 256) + lane);
      ax = fmaf(w, bf2f(mv.x), ax); ay = fmaf(w, bf2f(mv.y), ay);
      az = fmaf(w, bf2f(mv.z), az); aw_ = fmaf(w, bf2f(mv.w), aw_);
    }
  }
  ushort4 o;
  o.x = f2bf(ax); o.y = f2bf(ay); o.z = f2bf(az); o.w = f2bf(aw_);
  *((ushort4*)(msg + (size_t)node * 512 + dir * 256) + lane) = o;
}

// bf16 MFMA GEMM: C[M,N] = A[M,K] @ Bt[N,K]^T + bias. (GEMM3)
template <int ABF16, int OUT_MODE, int NT>
__global__ __launch_bounds__(512) void mfma_gemm_kernel(
    const void* __restrict__ Av, const short* __restrict__ Bt,
    const float* __restrict__ bias, const float* __restrict__ row_sum,
    void* __restrict__ Cv, int M, int N, int K) {
  __shared__ short As[64 * 64];
  __shared__ short Bs[NT * 64 * 64];
  int tid = threadIdx.x;
  int lane = tid & 63, wid = tid >> 6;  // 8 waves
  int wm = wid >> 2, wn = wid & 3;      // 2 x 4
  int m0 = blockIdx.x * 64, n0 = blockIdx.y * (64 * NT);

  f32x4 acc[2][NT];
#pragma unroll
  for (int m = 0; m < 2; ++m)
#pragma unroll
    for (int n = 0; n < NT; ++n) acc[m][n] = (f32x4){0.f, 0.f, 0.f, 0.f};

  int ar = tid >> 3;
  int ag = tid & 7;
  bool arow_ok = (m0 + ar) < M;

  for (int k0 = 0; k0 < K; k0 += 64) {
    if (ABF16) {
      const short8* ap =
          (const short8*)((const short*)Av + (size_t)(m0 + ar) * K + k0);
      short8 w = (short8){0, 0, 0, 0, 0, 0, 0, 0};
      if (arow_ok) w = ap[ag];
      *(short8*)&As[ar * 64 + ((ag ^ (ar & 7)) << 3)] = w;
    } else {
      const float4* ap =
          (const float4*)((const float*)Av + (size_t)(m0 + ar) * K + k0 + ag * 8);
      float4 u = make_float4(0.f, 0.f, 0.f, 0.f);
      float4 v = make_float4(0.f, 0.f, 0.f, 0.f);
      if (arow_ok) { u = ap[0]; v = ap[1]; }
      short8 w;
      w[0] = (short)f2bf(u.x); w[1] = (short)f2bf(u.y);
      w[2] = (short)f2bf(u.z); w[3] = (short)f2bf(u.w);
      w[4] = (short)f2bf(v.x); w[5] = (short)f2bf(v.y);
      w[6] = (short)f2bf(v.z); w[7] = (short)f2bf(v.w);
      *(short8*)&As[ar * 64 + ((ag ^ (ar & 7)) << 3)] = w;
    }
#pragma unroll
    for (int nt = 0; nt < NT; ++nt) {
      int r = nt * 64 + ar;
      const short8* bp = (const short8*)(Bt + (size_t)(n0 + r) * K + k0);
      short8 w = bp[ag];
      *(short8*)&Bs[r * 64 + ((ag ^ (r & 7)) << 3)] = w;
    }
    __syncthreads();
    int lsw = lane & 7, l15 = lane & 15, lk = lane >> 4;
#pragma unroll
    for (int kk = 0; kk < 2; ++kk) {
      int gg = kk * 4 + lk;
      int xo = ((gg ^ lsw) << 3);
      short8 af[2];
#pragma unroll
      for (int m = 0; m < 2; ++m)
        af[m] = *(const short8*)&As[(wm * 32 + m * 16 + l15) * 64 + xo];
#pragma unroll
      for (int f = 0; f < NT; ++f) {
        short8 bfr =
            *(const short8*)&Bs[(wn * NT * 16 + f * 16 + l15) * 64 + xo];
#pragma unroll
        for (int m = 0; m < 2; ++m)
          acc[m][f] = __builtin_amdgcn_mfma_f32_16x16x32_bf16(af[m], bfr,
                                                              acc[m][f], 0, 0, 0);
      }
    }
    __syncthreads();
  }
#pragma unroll
  for (int m = 0; m < 2; ++m) {
    int gmBase = m0 + wm * 32 + m * 16 + (lane >> 4) * 4;
#pragma unroll
    for (int f = 0; f < NT; ++f) {
      int gn = n0 + wn * NT * 16 + f * 16 + (lane & 15);
      float bv = bias[gn];
#pragma unroll
      for (int r = 0; r < 4; ++r) {
        int gm = gmBase + r;
        if (gm >= M) continue;
        float v = acc[m][f][r] + bv;
        if (OUT_MODE == 1) v = (row_sum[gm] > 0.0f) ? fmaxf(v, 0.0f) : 0.0f;
        if (OUT_MODE == 2)
          ((unsigned short*)Cv)[(size_t)gm * N + gn] = f2bf(v);
        else
          ((float*)Cv)[(size_t)gm * N + gn] = v;
      }
    }
  }
}

// GEMM2 fused with LayerNorm+ReLU: h1ln(bf16) = relu(LN(msg @ W1 + b1)).
__global__ __launch_bounds__(512) void gemm2_ln_kernel(
    const unsigned short* __restrict__ msg, const short* __restrict__ W1T,
    const float* __restrict__ b1, const float* __restrict__ gamma,
    const float* __restrict__ beta, unsigned short* __restrict__ h1ln,
    int M) {
  __shared__ short As[64 * 64];
  __shared__ short Bs[128 * 64];
  __shared__ float lnS[64][4];
  __shared__ float lnQ[64][4];
  const int K = 512;
  int tid = threadIdx.x;
  int lane = tid & 63, wid = tid >> 6;  // 8 waves
  int wm = wid >> 2, wn = wid & 3;      // 2m x 4n (4n x 32 cols = 128)
  int m0 = blockIdx.x * 64;

  f32x4 acc[2][2];
#pragma unroll
  for (int m = 0; m < 2; ++m)
#pragma unroll
    for (int n = 0; n < 2; ++n) acc[m][n] = (f32x4){0.f, 0.f, 0.f, 0.f};

  int ar = tid >> 3, ag = tid & 7;
  bool arow_ok = (m0 + ar) < M;
  int br = tid >> 2;       // B row 0..127
  int bg = (tid & 3) * 2;  // 2 k-groups each

  for (int k0 = 0; k0 < K; k0 += 64) {
    {
      const short8* ap =
          (const short8*)((const short*)msg + (size_t)(m0 + ar) * K + k0);
      short8 w = (short8){0, 0, 0, 0, 0, 0, 0, 0};
      if (arow_ok) w = ap[ag];
      *(short8*)&As[ar * 64 + ((ag ^ (ar & 7)) << 3)] = w;
    }
    {
      const short8* bp = (const short8*)(W1T + (size_t)br * K + k0);
#pragma unroll
      for (int g2 = 0; g2 < 2; ++g2) {
        int g = bg + g2;
        short8 w = bp[g];
        *(short8*)&Bs[br * 64 + ((g ^ (br & 7)) << 3)] = w;
      }
    }
    __syncthreads();
    int lsw = lane & 7, l15 = lane & 15, lk = lane >> 4;
#pragma unroll
    for (int kk = 0; kk < 2; ++kk) {
      int gg = kk * 4 + lk;
      int xo = ((gg ^ lsw) << 3);
      short8 af[2];
#pragma unroll
      for (int m = 0; m < 2; ++m)
        af[m] = *(const short8*)&As[(wm * 32 + m * 16 + l15) * 64 + xo];
#pragma unroll
      for (int n = 0; n < 2; ++n) {
        short8 bfr = *(const short8*)&Bs[(wn * 32 + n * 16 + l15) * 64 + xo];
#pragma unroll
        for (int m = 0; m < 2; ++m)
          acc[m][n] = __builtin_amdgcn_mfma_f32_16x16x32_bf16(af[m], bfr,
                                                              acc[m][n], 0, 0, 0);
      }
    }
    __syncthreads();
  }

  // --- LN epilogue ---
  int l15 = lane & 15, lg = lane >> 4;
  int c0 = wn * 32 + l15, c1 = c0 + 16;
  float bv0 = b1[c0], bv1 = b1[c1];
  float g0 = gamma[c0], g1 = gamma[c1];
  float be0 = beta[c0], be1 = beta[c1];
#pragma unroll
  for (int m = 0; m < 2; ++m) {
#pragma unroll
    for (int r = 0; r < 4; ++r) {
      float v0 = acc[m][0][r] + bv0, v1 = acc[m][1][r] + bv1;
      float s1 = v0 + v1;
      float s2 = v0 * v0 + v1 * v1;
#pragma unroll
      for (int mk = 1; mk < 16; mk <<= 1) {
        s1 += __shfl_xor(s1, mk, 64);
        s2 += __shfl_xor(s2, mk, 64);
      }
      int row_l = wm * 32 + m * 16 + lg * 4 + r;
      if (l15 == 0) {
        lnS[row_l][wn] = s1;
        lnQ[row_l][wn] = s2;
      }
    }
  }
  __syncthreads();
#pragma unroll
  for (int m = 0; m < 2; ++m) {
#pragma unroll
    for (int r = 0; r < 4; ++r) {
      int row_l = wm * 32 + m * 16 + lg * 4 + r;
      int gm = m0 + row_l;
      if (gm >= M) continue;
      float S = lnS[row_l][0] + lnS[row_l][1] + lnS[row_l][2] + lnS[row_l][3];
      float Q = lnQ[row_l][0] + lnQ[row_l][1] + lnQ[row_l][2] + lnQ[row_l][3];
      float mu = S * 0.0078125f;             // /128
      float var = Q * 0.0078125f - mu * mu;  // E[x^2]-mu^2
      float rs = rsqrtf(var + 1e-5f);
      float v0 = acc[m][0][r] + bv0, v1 = acc[m][1][r] + bv1;
      float y0 = fmaxf((v0 - mu) * rs * g0 + be0, 0.0f);
      float y1 = fmaxf((v1 - mu) * rs * g1 + be1, 0.0f);
      h1ln[(size_t)gm * 128 + c0] = f2bf(y0);
      h1ln[(size_t)gm * 128 + c1] = f2bf(y1);
    }
  }
}

extern "C" void kernel_launch(void* const* d_in, const int* in_sizes, int n_in,
                              void* d_out, int out_size, void* d_ws,
                              size_t ws_size, hipStream_t stream) {
  const float* src_feat = (const float*)d_in[0];
  const float* gate = (const float*)d_in[1];
  const int* idx = (const int*)d_in[2];
  const float* Wm = (const float*)d_in[3];
  const float* bm = (const float*)d_in[4];
  const float* W1 = (const float*)d_in[5];
  const float* b1 = (const float*)d_in[6];
  const float* gamma = (const float*)d_in[7];
  const float* beta = (const float*)d_in[8];
  const float* W2 = (const float*)d_in[9];
  const float* b2 = (const float*)d_in[10];
  float* out = (float*)d_out;

  const int D = 512;
  const int Nn = in_sizes[0] / D;  // 20000
  const int E = in_sizes[1];       // 200000

  char* ws = (char*)d_ws;
  size_t off = 0;
  auto alloc = [&](size_t bytes) {
    void* p = ws + off;
    off = (off + bytes + 255) & ~(size_t)255;
    return p;
  };
  // zero-region: combined (u64) + deg_dst (contiguous)
  unsigned long long* combined = (unsigned long long*)alloc((size_t)Nn * 8);
  int* deg_dst = (int*)alloc((size_t)Nn * 4);
  char* z_end = ws + off;
  float* row_sum = (float*)alloc((size_t)Nn * 4);  // written by scan_part
  float* exp_e = (float*)alloc((size_t)E * 4);
  int* rank_src = (int*)alloc((size_t)E * 4);
  int* rank_dst = (int*)alloc((size_t)E * 4);
  unsigned short* Mfeat = (unsigned short*)alloc((size_t)Nn * 256 * 2);
  unsigned short* msg = (unsigned short*)alloc((size_t)Nn * 512 * 2);
  unsigned short* h1ln = (unsigned short*)alloc((size_t)Nn * 128 * 2);
  short* WmT = (short*)alloc((size_t)512 * 256 * 2);
  short* W1T = (short*)alloc((size_t)512 * 128 * 2);
  short* W2T = (short*)alloc((size_t)128 * 512 * 2);
  int* off_src = (int*)alloc((size_t)(Nn + 1) * 4);
  int* off_dst = (int*)alloc((size_t)(Nn + 1) * 4);
  int2* pair_src = (int2*)alloc((size_t)E * 8);
  int2* pair_dst = (int2*)alloc((size_t)E * 8);
  int* sumsA = (int*)alloc(64 * 4);
  int* sumsB = (int*)alloc(64 * 4);

  int n1 = (int)((z_end - (char*)combined) >> 2);
  init_kernel<<<1024, 256, 0, stream>>>((unsigned int*)combined, n1, Wm, WmT,
                                        W1, W1T, W2, W2T);

  int gx = (Nn + 63) / 64;           // 313
  int gemmBlocks = gx * 2;           // 626 (NT=2, 2 n-tiles)
  int edgeBlocks = (E + 511) / 512;  // 391 (1 edge/thread)
  int totBlocks = gemmBlocks + edgeBlocks;  // 1017
  // Role-interleaved fused launch: edge and GEMM blocks Bresenham-mixed
  gemm1_edge_kernel<<<totBlocks, 512, 0, stream>>>(
      src_feat, WmT, bm, Mfeat, Nn, edgeBlocks, totBlocks, gate, idx, exp_e,
      combined, deg_dst, rank_src, rank_dst, E);

  int nb = (Nn + 1023) / 1024;  // 20
  scan_part_kernel<<<nb, 1024, 0, stream>>>(combined, deg_dst, row_sum,
                                            off_src, off_dst, sumsA, sumsB,
                                            Nn);
  scan_fixup_kernel<<<nb, 1024, 0, stream>>>(off_src, off_dst, sumsA, sumsB,
                                             Nn, nb);
  // scatter: NO atomics (rank-based slots), packed int2 pairs
  scatter_ids_kernel<<<(E + 511) / 512, 256, 0, stream>>>(
      idx, exp_e, row_sum, off_src, off_dst, rank_src, rank_dst, pair_src,
      pair_dst, E);
  // aggregate: one wave per (node, dir) -> 40000 waves
  aggregate_kernel<<<(2 * Nn + 3) / 4, 256, 0, stream>>>(
      off_src, pair_src, off_dst, pair_dst, Mfeat, msg, Nn);
  // GEMM2 + LN + ReLU fused: h1ln(bf16) = relu(LN(msg @ W1 + b1))
  gemm2_ln_kernel<<<gx, 512, 0, stream>>>(msg, W1T, b1, gamma, beta, h1ln, Nn);
  // GEMM3: out(f32) = h1ln(bf16) @ W2 + b2, relu+mask  [M=Nn,N=512,K=128],
  //        NT=4, y=2
  mfma_gemm_kernel<1, 1, 4><<<dim3(gx, 2), 512, 0, stream>>>(
      h1ln, W2T, b2, row_sum, out, Nn, 512, 128);
}

// Round 26
// 109.820 us; speedup vs baseline: 1.0659x; 1.0080x over previous
//
#include <hip/hip_runtime.h>
#include <math.h>

// ---------------------------------------------------------------------------
// MessageGenerator: edge-softmax attention message passing + MLP head.
// N=20000 nodes, E=200000 edges, D=512, Dm=256, Dh=128, H=512.
// R1-R24: see history. R24 = 110.7us (best).
// R25: 2-replica atomics (rep=e&1) for combined/deg_dst halve same-address
//      RMW chain depth (mean degree 10 -> 5 per replica). Rank trick kept:
//      scan_part emits per-node replica-0 counts; scatter rebases replica-1
//      ranks. Fixed-point row_sum fold is exact (integer adds).
// ---------------------------------------------------------------------------

typedef __attribute__((ext_vector_type(8))) short short8;
typedef __attribute__((ext_vector_type(4))) float f32x4;

#define M_SHIFT 4.75f  // const softmax shift; only couples via +1e-6 eps
#define RS_SCALE 1099511627776.0  // 2^40
#define RS_MASK ((1ULL << 49) - 1)

static __device__ __forceinline__ unsigned short f2bf(float f) {
  union { float f; unsigned int u; } v; v.f = f;
  unsigned int r = v.u + 0x7fffu + ((v.u >> 16) & 1u);  // round-nearest-even
  return (unsigned short)(r >> 16);
}
static __device__ __forceinline__ float bf2f(unsigned short b) {
  union { unsigned int u; float f; } v; v.u = ((unsigned int)b) << 16;
  return v.f;
}

// Zero one dword region + transpose/convert all three weights. One launch.
__global__ void init_kernel(unsigned int* __restrict__ z1, int n1,
                            const float* __restrict__ Wm,
                            short* __restrict__ WmT,
                            const float* __restrict__ W1,
                            short* __restrict__ W1T,
                            const float* __restrict__ W2,
                            short* __restrict__ W2T) {
  int i = blockIdx.x * 256 + threadIdx.x;
  int stride = gridDim.x * 256;
  for (int j = i; j < n1; j += stride) z1[j] = 0u;
  if (i < 131072) {
    int n = i >> 9, k = i & 511;  // K=512, N=256
    WmT[i] = (short)f2bf(Wm[(size_t)k * 256 + n]);
  } else if (i < 196608) {
    int j = i - 131072;
    int n = j >> 9, k = j & 511;  // K=512, N=128
    W1T[j] = (short)f2bf(W1[(size_t)k * 128 + n]);
  } else if (i < 262144) {
    int j = i - 196608;
    int n = j >> 7, k = j & 127;  // K=128, N=512
    W2T[j] = (short)f2bf(W2[(size_t)k * 512 + n]);
  }
}

// Fused, role-INTERLEAVED (Bresenham). Edge part: 2-replica atomics
// (rep = e&1), ranks are replica-local (rebased in scatter).
__global__ __launch_bounds__(512) void gemm1_edge_kernel(
    const float* __restrict__ Av, const short* __restrict__ Bt,
    const float* __restrict__ bias, unsigned short* __restrict__ Cv, int M,
    int nEdge, int nTot, const float* __restrict__ gate,
    const int* __restrict__ idx, float* __restrict__ exp_e,
    unsigned long long* __restrict__ combined, int* __restrict__ deg_dst,
    int* __restrict__ rank_src, int* __restrict__ rank_dst, int E, int Nn) {
  const int N = 256, K = 512;
  __shared__ short As[64 * 64];
  __shared__ short Bs[2 * 64 * 64];
  int bid = (int)blockIdx.x;
  long long lo = (long long)bid * nEdge / nTot;
  long long hi = (long long)(bid + 1) * nEdge / nTot;
  if (hi > lo) {
    // --- edge_exp block: eid = lo, 1 edge/thread, 2-replica atomics ---
    int e = (int)lo * 512 + threadIdx.x;
    if (e < E) {
      float v = expf(gate[e] - M_SHIFT);
      exp_e[e] = v;
      int s = idx[2 * e], d = idx[2 * e + 1];
      int rep = e & 1;
      unsigned long long fx = (unsigned long long)((double)v * RS_SCALE);
      unsigned long long oldc =
          atomicAdd(&combined[(size_t)rep * Nn + s], (1ULL << 49) | fx);
      int oldd = atomicAdd(&deg_dst[rep * Nn + d], 1);
      rank_src[e] = (int)(oldc >> 49);
      rank_dst[e] = oldd;
    }
    return;
  }
  // --- GEMM1 block: gid = bid - lo ---
  int blk = bid - (int)lo;
  int tid = threadIdx.x;
  int lane = tid & 63, wid = tid >> 6;
  int wm = wid >> 2, wn = wid & 3;
  int m0 = (blk >> 1) * 64;
  int n0 = (blk & 1) * 128;

  f32x4 acc[2][2];
#pragma unroll
  for (int m = 0; m < 2; ++m)
#pragma unroll
    for (int n = 0; n < 2; ++n) acc[m][n] = (f32x4){0.f, 0.f, 0.f, 0.f};

  int ar = tid >> 3, ag = tid & 7;
  bool arow_ok = (m0 + ar) < M;

  for (int k0 = 0; k0 < K; k0 += 64) {
    {
      const float4* ap =
          (const float4*)(Av + (size_t)(m0 + ar) * K + k0 + ag * 8);
      float4 u = make_float4(0.f, 0.f, 0.f, 0.f);
      float4 v = make_float4(0.f, 0.f, 0.f, 0.f);
      if (arow_ok) { u = ap[0]; v = ap[1]; }
      short8 w;
      w[0] = (short)f2bf(u.x); w[1] = (short)f2bf(u.y);
      w[2] = (short)f2bf(u.z); w[3] = (short)f2bf(u.w);
      w[4] = (short)f2bf(v.x); w[5] = (short)f2bf(v.y);
      w[6] = (short)f2bf(v.z); w[7] = (short)f2bf(v.w);
      *(short8*)&As[ar * 64 + ((ag ^ (ar & 7)) << 3)] = w;
    }
#pragma unroll
    for (int nt = 0; nt < 2; ++nt) {
      int r = nt * 64 + ar;
      const short8* bp = (const short8*)(Bt + (size_t)(n0 + r) * K + k0);
      short8 w = bp[ag];
      *(short8*)&Bs[r * 64 + ((ag ^ (r & 7)) << 3)] = w;
    }
    __syncthreads();
    int lsw = lane & 7, l15 = lane & 15, lk = lane >> 4;
#pragma unroll
    for (int kk = 0; kk < 2; ++kk) {
      int gg = kk * 4 + lk;
      int xo = ((gg ^ lsw) << 3);
      short8 af[2];
#pragma unroll
      for (int m = 0; m < 2; ++m)
        af[m] = *(const short8*)&As[(wm * 32 + m * 16 + l15) * 64 + xo];
#pragma unroll
      for (int f = 0; f < 2; ++f) {
        short8 bfr =
            *(const short8*)&Bs[(wn * 32 + f * 16 + l15) * 64 + xo];
#pragma unroll
        for (int m = 0; m < 2; ++m)
          acc[m][f] = __builtin_amdgcn_mfma_f32_16x16x32_bf16(af[m], bfr,
                                                              acc[m][f], 0, 0, 0);
      }
    }
    __syncthreads();
  }
#pragma unroll
  for (int m = 0; m < 2; ++m) {
    int gmBase = m0 + wm * 32 + m * 16 + (lane >> 4) * 4;
#pragma unroll
    for (int f = 0; f < 2; ++f) {
      int gn = n0 + wn * 32 + f * 16 + (lane & 15);
      float bv = bias[gn];
#pragma unroll
      for (int r = 0; r < 4; ++r) {
        int gm = gmBase + r;
        if (gm >= M) continue;
        Cv[(size_t)gm * N + gn] = f2bf(acc[m][f][r] + bv);
      }
    }
  }
}

// Phase 1: fold 2 replicas; decode -> (deg totals, row_sum, replica-0
// counts); per-block exclusive scan of totals.
__global__ __launch_bounds__(1024) void scan_part_kernel(
    const unsigned long long* __restrict__ combined,
    const int* __restrict__ degB, float* __restrict__ row_sum,
    int* __restrict__ cnt_src0, int* __restrict__ cnt_dst0,
    int* __restrict__ offA, int* __restrict__ offB, int* __restrict__ sumsA,
    int* __restrict__ sumsB, int n) {
  __shared__ int tA[1024], tB[1024];
  int b = blockIdx.x, t = threadIdx.x;
  int i = b * 1024 + t;
  int vA = 0, vB = 0;
  if (i < n) {
    unsigned long long c0 = combined[i];
    unsigned long long c1 = combined[(size_t)n + i];
    int a0 = (int)(c0 >> 49), a1 = (int)(c1 >> 49);
    vA = a0 + a1;
    cnt_src0[i] = a0;
    row_sum[i] =
        (float)((double)((c0 & RS_MASK) + (c1 & RS_MASK)) * (1.0 / RS_SCALE));
    int b0 = degB[i], b1 = degB[n + i];
    vB = b0 + b1;
    cnt_dst0[i] = b0;
  }
  tA[t] = vA;
  tB[t] = vB;
  __syncthreads();
  for (int off = 1; off < 1024; off <<= 1) {
    int xA = (t >= off) ? tA[t - off] : 0;
    int xB = (t >= off) ? tB[t - off] : 0;
    __syncthreads();
    tA[t] += xA;
    tB[t] += xB;
    __syncthreads();
  }
  if (i < n) {
    offA[i] = tA[t] - vA;  // block-local exclusive
    offB[i] = tB[t] - vB;
  }
  if (t == 1023) {
    sumsA[b] = tA[t];
    sumsB[b] = tB[t];
  }
}

// Phase 2: add carry of preceding blocks.
__global__ __launch_bounds__(1024) void scan_fixup_kernel(
    int* __restrict__ offA, int* __restrict__ offB,
    const int* __restrict__ sumsA, const int* __restrict__ sumsB, int n,
    int nb) {
  __shared__ int cA, cB;
  int b = blockIdx.x, t = threadIdx.x;
  if (t == 0) {
    int ca = 0, cb = 0;
    for (int j = 0; j < b; ++j) {
      ca += sumsA[j];
      cb += sumsB[j];
    }
    cA = ca;
    cB = cb;
  }
  __syncthreads();
  int i = b * 1024 + t;
  if (i < n) {
    offA[i] += cA;
    offB[i] += cB;
  }
  if (b == nb - 1 && t == 0) {
    offA[n] = cA + sumsA[b];
    offB[n] = cB + sumsB[b];
  }
}

// Scatter via replica-rebased ranks — NO atomics. slot = off[node] +
// (rep ? cnt0[node] : 0) + replica-local rank. Packed int2 pairs.
__global__ void scatter_ids_kernel(const int* __restrict__ idx,
                                   const float* __restrict__ exp_e,
                                   const float* __restrict__ row_sum,
                                   const int* __restrict__ off_src,
                                   const int* __restrict__ off_dst,
                                   const int* __restrict__ cnt_src0,
                                   const int* __restrict__ cnt_dst0,
                                   const int* __restrict__ rank_src,
                                   const int* __restrict__ rank_dst,
                                   int2* __restrict__ pair_src,
                                   int2* __restrict__ pair_dst, int E) {
  int base = blockIdx.x * 512;
  int e0 = base + threadIdx.x;
  int e1 = e0 + 256;
#pragma unroll
  for (int k = 0; k < 2; ++k) {
    int e = k ? e1 : e0;
    if (e >= E) continue;
    int s = idx[2 * e], d = idx[2 * e + 1];
    int rep = e & 1;
    float a = exp_e[e] / (row_sum[s] + 1e-6f);
    int ai = __float_as_int(a);
    int bs = off_src[s] + (rep ? cnt_src0[s] : 0) + rank_src[e];
    int bd = off_dst[d] + (rep ? cnt_dst0[d] : 0) + rank_dst[e];
    pair_src[bs] = make_int2(d, ai);
    pair_dst[bd] = make_int2(s, ai);
  }
}

// One wave per (node, direction); unroll ladder 8/4/2/1. Metadata = one
// int2 (oth, att) load per slot.
__global__ __launch_bounds__(256) void aggregate_kernel(
    const int* __restrict__ off_src, const int2* __restrict__ pair_src,
    const int* __restrict__ off_dst, const int2* __restrict__ pair_dst,
    const unsigned short* __restrict__ Mfeat, unsigned short* __restrict__ msg,
    int Nn) {
  int slot = blockIdx.x * 4 + (threadIdx.x >> 6);
  int node = slot >> 1, dir = slot & 1;
  if (node >= Nn) return;
  int lane = threadIdx.x & 63;
  const int* offp = dir ? off_dst : off_src;
  const int2* pp = dir ? pair_dst : pair_src;
  float ax = 0.f, ay = 0.f, az = 0.f, aw_ = 0.f;
  int b0 = offp[node], e0 = offp[node + 1];
  for (int base = b0; base < e0; base += 64) {
    int cnt = min(64, e0 - base);
    int2 pr = (lane < cnt) ? pp[base + lane] : make_int2(0, 0);
    int oth = pr.x;
    float wv = __int_as_float(pr.y);
    if (lane >= cnt) wv = 0.0f;
    int t = 0;
    for (; t + 8 <= cnt; t += 8) {
      int r0 = __shfl(oth, t, 64), r1 = __shfl(oth, t + 1, 64);
      int r2 = __shfl(oth, t + 2, 64), r3 = __shfl(oth, t + 3, 64);
      int r4 = __shfl(oth, t + 4, 64), r5 = __shfl(oth, t + 5, 64);
      int r6 = __shfl(oth, t + 6, 64), r7 = __shfl(oth, t + 7, 64);
      float w0 = __shfl(wv, t, 64), w1 = __shfl(wv, t + 1, 64);
      float w2 = __shfl(wv, t + 2, 64), w3 = __shfl(wv, t + 3, 64);
      float w4 = __shfl(wv, t + 4, 64), w5 = __shfl(wv, t + 5, 64);
      float w6 = __shfl(wv, t + 6, 64), w7 = __shfl(wv, t + 7, 64);
      ushort4 m0 = *((const ushort4*)(Mfeat + (size_t)r0 * 256) + lane);
      ushort4 m1 = *((const ushort4*)(Mfeat + (size_t)r1 * 256) + lane);
      ushort4 m2 = *((const ushort4*)(Mfeat + (size_t)r2 * 256) + lane);
      ushort4 m3 = *((const ushort4*)(Mfeat + (size_t)r3 * 256) + lane);
      ushort4 m4 = *((const ushort4*)(Mfeat + (size_t)r4 * 256) + lane);
      ushort4 m5 = *((const ushort4*)(Mfeat + (size_t)r5 * 256) + lane);
      ushort4 m6 = *((const ushort4*)(Mfeat + (size_t)r6 * 256) + lane);
      ushort4 m7 = *((const ushort4*)(Mfeat + (size_t)r7 * 256) + lane);
      ax = fmaf(w0, bf2f(m0.x), ax); ay = fmaf(w0, bf2f(m0.y), ay);
      az = fmaf(w0, bf2f(m0.z), az); aw_ = fmaf(w0, bf2f(m0.w), aw_);
      ax = fmaf(w1, bf2f(m1.x), ax); ay = fmaf(w1, bf2f(m1.y), ay);
      az = fmaf(w1, bf2f(m1.z), az); aw_ = fmaf(w1, bf2f(m1.w), aw_);
      ax = fmaf(w2, bf2f(m2.x), ax); ay = fmaf(w2, bf2f(m2.y), ay);
      az = fmaf(w2, bf2f(m2.z), az); aw_ = fmaf(w2, bf2f(m2.w), aw_);
      ax = fmaf(w3, bf2f(m3.x), ax); ay = fmaf(w3, bf2f(m3.y), ay);
      az = fmaf(w3, bf2f(m3.z), az); aw_ = fmaf(w3, bf2f(m3.w), aw_);
      ax = fmaf(w4, bf2f(m4.x), ax); ay = fmaf(w4, bf2f(m4.y), ay);
      az = fmaf(w4, bf2f(m4.z), az); aw_ = fmaf(w4, bf2f(m4.w), aw_);
      ax = fmaf(w5, bf2f(m5.x), ax); ay = fmaf(w5, bf2f(m5.y), ay);
      az = fmaf(w5, bf2f(m5.z), az); aw_ = fmaf(w5, bf2f(m5.w), aw_);
      ax = fmaf(w6, bf2f(m6.x), ax); ay = fmaf(w6, bf2f(m6.y), ay);
      az = fmaf(w6, bf2f(m6.z), az); aw_ = fmaf(w6, bf2f(m6.w), aw_);
      ax = fmaf(w7, bf2f(m7.x), ax); ay = fmaf(w7, bf2f(m7.y), ay);
      az = fmaf(w7, bf2f(m7.z), az); aw_ = fmaf(w7, bf2f(m7.w), aw_);
    }
    for (; t + 4 <= cnt; t += 4) {
      int r0 = __shfl(oth, t, 64), r1 = __shfl(oth, t + 1, 64);
      int r2 = __shfl(oth, t + 2, 64), r3 = __shfl(oth, t + 3, 64);
      float w0 = __shfl(wv, t, 64), w1 = __shfl(wv, t + 1, 64);
      float w2 = __shfl(wv, t + 2, 64), w3 = __shfl(wv, t + 3, 64);
      ushort4 m0 = *((const ushort4*)(Mfeat + (size_t)r0 * 256) + lane);
      ushort4 m1 = *((const ushort4*)(Mfeat + (size_t)r1 * 256) + lane);
      ushort4 m2 = *((const ushort4*)(Mfeat + (size_t)r2 * 256) + lane);
      ushort4 m3 = *((const ushort4*)(Mfeat + (size_t)r3 * 256) + lane);
      ax = fmaf(w0, bf2f(m0.x), ax); ay = fmaf(w0, bf2f(m0.y), ay);
      az = fmaf(w0, bf2f(m0.z), az); aw_ = fmaf(w0, bf2f(m0.w), aw_);
      ax = fmaf(w1, bf2f(m1.x), ax); ay = fmaf(w1, bf2f(m1.y), ay);
      az = fmaf(w1, bf2f(m1.z), az); aw_ = fmaf(w1, bf2f(m1.w), aw_);
      ax = fmaf(w2, bf2f(m2.x), ax); ay = fmaf(w2, bf2f(m2.y), ay);
      az = fmaf(w2, bf2f(m2.z), az); aw_ = fmaf(w2, bf2f(m2.w), aw_);
      ax = fmaf(w3, bf2f(m3.x), ax); ay = fmaf(w3, bf2f(m3.y), ay);
      az = fmaf(w3, bf2f(m3.z), az); aw_ = fmaf(w3, bf2f(m3.w), aw_);
    }
    for (; t + 2 <= cnt; t += 2) {
      int r0 = __shfl(oth, t, 64), r1 = __shfl(oth, t + 1, 64);
      float w0 = __shfl(wv, t, 64), w1 = __shfl(wv, t + 1, 64);
      ushort4 m0 = *((const ushort4*)(Mfeat + (size_t)r0 * 256) + lane);
      ushort4 m1 = *((const ushort4*)(Mfeat + (size_t)r1 * 256) + lane);
      ax = fmaf(w0, bf2f(m0.x), ax); ay = fmaf(w0, bf2f(m0.y), ay);
      az = fmaf(w0, bf2f(m0.z), az); aw_ = fmaf(w0, bf2f(m0.w), aw_);
      ax = fmaf(w1, bf2f(m1.x), ax); ay = fmaf(w1, bf2f(m1.y), ay);
      az = fmaf(w1, bf2f(m1.z), az); aw_ = fmaf(w1, bf2f(m1.w), aw_);
    }
    for (; t < cnt; ++t) {
      int r = __shfl(oth, t, 64);
      float w = __shfl(wv, t, 64);
      ushort4 mv = *((const ushort4*)(Mfeat + (size_t)r * 256) + lane);
      ax = fmaf(w, bf2f(mv.x), ax); ay = fmaf(w, bf2f(mv.y), ay);
      az = fmaf(w, bf2f(mv.z), az); aw_ = fmaf(w, bf2f(mv.w), aw_);
    }
  }
  ushort4 o;
  o.x = f2bf(ax); o.y = f2bf(ay); o.z = f2bf(az); o.w = f2bf(aw_);
  *((ushort4*)(msg + (size_t)node * 512 + dir * 256) + lane) = o;
}

// bf16 MFMA GEMM: C[M,N] = A[M,K] @ Bt[N,K]^T + bias. (GEMM3)
template <int ABF16, int OUT_MODE, int NT>
__global__ __launch_bounds__(512) void mfma_gemm_kernel(
    const void* __restrict__ Av, const short* __restrict__ Bt,
    const float* __restrict__ bias, const float* __restrict__ row_sum,
    void* __restrict__ Cv, int M, int N, int K) {
  __shared__ short As[64 * 64];
  __shared__ short Bs[NT * 64 * 64];
  int tid = threadIdx.x;
  int lane = tid & 63, wid = tid >> 6;  // 8 waves
  int wm = wid >> 2, wn = wid & 3;      // 2 x 4
  int m0 = blockIdx.x * 64, n0 = blockIdx.y * (64 * NT);

  f32x4 acc[2][NT];
#pragma unroll
  for (int m = 0; m < 2; ++m)
#pragma unroll
    for (int n = 0; n < NT; ++n) acc[m][n] = (f32x4){0.f, 0.f, 0.f, 0.f};

  int ar = tid >> 3;
  int ag = tid & 7;
  bool arow_ok = (m0 + ar) < M;

  for (int k0 = 0; k0 < K; k0 += 64) {
    if (ABF16) {
      const short8* ap =
          (const short8*)((const short*)Av + (size_t)(m0 + ar) * K + k0);
      short8 w = (short8){0, 0, 0, 0, 0, 0, 0, 0};
      if (arow_ok) w = ap[ag];
      *(short8*)&As[ar * 64 + ((ag ^ (ar & 7)) << 3)] = w;
    } else {
      const float4* ap =
          (const float4*)((const float*)Av + (size_t)(m0 + ar) * K + k0 + ag * 8);
      float4 u = make_float4(0.f, 0.f, 0.f, 0.f);
      float4 v = make_float4(0.f, 0.f, 0.f, 0.f);
      if (arow_ok) { u = ap[0]; v = ap[1]; }
      short8 w;
      w[0] = (short)f2bf(u.x); w[1] = (short)f2bf(u.y);
      w[2] = (short)f2bf(u.z); w[3] = (short)f2bf(u.w);
      w[4] = (short)f2bf(v.x); w[5] = (short)f2bf(v.y);
      w[6] = (short)f2bf(v.z); w[7] = (short)f2bf(v.w);
      *(short8*)&As[ar * 64 + ((ag ^ (ar & 7)) << 3)] = w;
    }
#pragma unroll
    for (int nt = 0; nt < NT; ++nt) {
      int r = nt * 64 + ar;
      const short8* bp = (const short8*)(Bt + (size_t)(n0 + r) * K + k0);
      short8 w = bp[ag];
      *(short8*)&Bs[r * 64 + ((ag ^ (r & 7)) << 3)] = w;
    }
    __syncthreads();
    int lsw = lane & 7, l15 = lane & 15, lk = lane >> 4;
#pragma unroll
    for (int kk = 0; kk < 2; ++kk) {
      int gg = kk * 4 + lk;
      int xo = ((gg ^ lsw) << 3);
      short8 af[2];
#pragma unroll
      for (int m = 0; m < 2; ++m)
        af[m] = *(const short8*)&As[(wm * 32 + m * 16 + l15) * 64 + xo];
#pragma unroll
      for (int f = 0; f < NT; ++f) {
        short8 bfr =
            *(const short8*)&Bs[(wn * NT * 16 + f * 16 + l15) * 64 + xo];
#pragma unroll
        for (int m = 0; m < 2; ++m)
          acc[m][f] = __builtin_amdgcn_mfma_f32_16x16x32_bf16(af[m], bfr,
                                                              acc[m][f], 0, 0, 0);
      }
    }
    __syncthreads();
  }
#pragma unroll
  for (int m = 0; m < 2; ++m) {
    int gmBase = m0 + wm * 32 + m * 16 + (lane >> 4) * 4;
#pragma unroll
    for (int f = 0; f < NT; ++f) {
      int gn = n0 + wn * NT * 16 + f * 16 + (lane & 15);
      float bv = bias[gn];
#pragma unroll
      for (int r = 0; r < 4; ++r) {
        int gm = gmBase + r;
        if (gm >= M) continue;
        float v = acc[m][f][r] + bv;
        if (OUT_MODE == 1) v = (row_sum[gm] > 0.0f) ? fmaxf(v, 0.0f) : 0.0f;
        if (OUT_MODE == 2)
          ((unsigned short*)Cv)[(size_t)gm * N + gn] = f2bf(v);
        else
          ((float*)Cv)[(size_t)gm * N + gn] = v;
      }
    }
  }
}

// GEMM2 fused with LayerNorm+ReLU: h1ln(bf16) = relu(LN(msg @ W1 + b1)).
__global__ __launch_bounds__(512) void gemm2_ln_kernel(
    const unsigned short* __restrict__ msg, const short* __restrict__ W1T,
    const float* __restrict__ b1, const float* __restrict__ gamma,
    const float* __restrict__ beta, unsigned short* __restrict__ h1ln,
    int M) {
  __shared__ short As[64 * 64];
  __shared__ short Bs[128 * 64];
  __shared__ float lnS[64][4];
  __shared__ float lnQ[64][4];
  const int K = 512;
  int tid = threadIdx.x;
  int lane = tid & 63, wid = tid >> 6;  // 8 waves
  int wm = wid >> 2, wn = wid & 3;      // 2m x 4n (4n x 32 cols = 128)
  int m0 = blockIdx.x * 64;

  f32x4 acc[2][2];
#pragma unroll
  for (int m = 0; m < 2; ++m)
#pragma unroll
    for (int n = 0; n < 2; ++n) acc[m][n] = (f32x4){0.f, 0.f, 0.f, 0.f};

  int ar = tid >> 3, ag = tid & 7;
  bool arow_ok = (m0 + ar) < M;
  int br = tid >> 2;       // B row 0..127
  int bg = (tid & 3) * 2;  // 2 k-groups each

  for (int k0 = 0; k0 < K; k0 += 64) {
    {
      const short8* ap =
          (const short8*)((const short*)msg + (size_t)(m0 + ar) * K + k0);
      short8 w = (short8){0, 0, 0, 0, 0, 0, 0, 0};
      if (arow_ok) w = ap[ag];
      *(short8*)&As[ar * 64 + ((ag ^ (ar & 7)) << 3)] = w;
    }
    {
      const short8* bp = (const short8*)(W1T + (size_t)br * K + k0);
#pragma unroll
      for (int g2 = 0; g2 < 2; ++g2) {
        int g = bg + g2;
        short8 w = bp[g];
        *(short8*)&Bs[br * 64 + ((g ^ (br & 7)) << 3)] = w;
      }
    }
    __syncthreads();
    int lsw = lane & 7, l15 = lane & 15, lk = lane >> 4;
#pragma unroll
    for (int kk = 0; kk < 2; ++kk) {
      int gg = kk * 4 + lk;
      int xo = ((gg ^ lsw) << 3);
      short8 af[2];
#pragma unroll
      for (int m = 0; m < 2; ++m)
        af[m] = *(const short8*)&As[(wm * 32 + m * 16 + l15) * 64 + xo];
#pragma unroll
      for (int n = 0; n < 2; ++n) {
        short8 bfr = *(const short8*)&Bs[(wn * 32 + n * 16 + l15) * 64 + xo];
#pragma unroll
        for (int m = 0; m < 2; ++m)
          acc[m][n] = __builtin_amdgcn_mfma_f32_16x16x32_bf16(af[m], bfr,
                                                              acc[m][n], 0, 0, 0);
      }
    }
    __syncthreads();
  }

  // --- LN epilogue ---
  int l15 = lane & 15, lg = lane >> 4;
  int c0 = wn * 32 + l15, c1 = c0 + 16;
  float bv0 = b1[c0], bv1 = b1[c1];
  float g0 = gamma[c0], g1 = gamma[c1];
  float be0 = beta[c0], be1 = beta[c1];
#pragma unroll
  for (int m = 0; m < 2; ++m) {
#pragma unroll
    for (int r = 0; r < 4; ++r) {
      float v0 = acc[m][0][r] + bv0, v1 = acc[m][1][r] + bv1;
      float s1 = v0 + v1;
      float s2 = v0 * v0 + v1 * v1;
#pragma unroll
      for (int mk = 1; mk < 16; mk <<= 1) {
        s1 += __shfl_xor(s1, mk, 64);
        s2 += __shfl_xor(s2, mk, 64);
      }
      int row_l = wm * 32 + m * 16 + lg * 4 + r;
      if (l15 == 0) {
        lnS[row_l][wn] = s1;
        lnQ[row_l][wn] = s2;
      }
    }
  }
  __syncthreads();
#pragma unroll
  for (int m = 0; m < 2; ++m) {
#pragma unroll
    for (int r = 0; r < 4; ++r) {
      int row_l = wm * 32 + m * 16 + lg * 4 + r;
      int gm = m0 + row_l;
      if (gm >= M) continue;
      float S = lnS[row_l][0] + lnS[row_l][1] + lnS[row_l][2] + lnS[row_l][3];
      float Q = lnQ[row_l][0] + lnQ[row_l][1] + lnQ[row_l][2] + lnQ[row_l][3];
      float mu = S * 0.0078125f;             // /128
      float var = Q * 0.0078125f - mu * mu;  // E[x^2]-mu^2
      float rs = rsqrtf(var + 1e-5f);
      float v0 = acc[m][0][r] + bv0, v1 = acc[m][1][r] + bv1;
      float y0 = fmaxf((v0 - mu) * rs * g0 + be0, 0.0f);
      float y1 = fmaxf((v1 - mu) * rs * g1 + be1, 0.0f);
      h1ln[(size_t)gm * 128 + c0] = f2bf(y0);
      h1ln[(size_t)gm * 128 + c1] = f2bf(y1);
    }
  }
}

extern "C" void kernel_launch(void* const* d_in, const int* in_sizes, int n_in,
                              void* d_out, int out_size, void* d_ws,
                              size_t ws_size, hipStream_t stream) {
  const float* src_feat = (const float*)d_in[0];
  const float* gate = (const float*)d_in[1];
  const int* idx = (const int*)d_in[2];
  const float* Wm = (const float*)d_in[3];
  const float* bm = (const float*)d_in[4];
  const float* W1 = (const float*)d_in[5];
  const float* b1 = (const float*)d_in[6];
  const float* gamma = (const float*)d_in[7];
  const float* beta = (const float*)d_in[8];
  const float* W2 = (const float*)d_in[9];
  const float* b2 = (const float*)d_in[10];
  float* out = (float*)d_out;

  const int D = 512;
  const int Nn = in_sizes[0] / D;  // 20000
  const int E = in_sizes[1];       // 200000

  char* ws = (char*)d_ws;
  size_t off = 0;
  auto alloc = [&](size_t bytes) {
    void* p = ws + off;
    off = (off + bytes + 255) & ~(size_t)255;
    return p;
  };
  // zero-region: combined (2 replicas u64) + deg_dst (2 replicas int)
  unsigned long long* combined =
      (unsigned long long*)alloc((size_t)Nn * 2 * 8);
  int* deg_dst = (int*)alloc((size_t)Nn * 2 * 4);
  char* z_end = ws + off;
  float* row_sum = (float*)alloc((size_t)Nn * 4);  // written by scan_part
  int* cnt_src0 = (int*)alloc((size_t)Nn * 4);
  int* cnt_dst0 = (int*)alloc((size_t)Nn * 4);
  float* exp_e = (float*)alloc((size_t)E * 4);
  int* rank_src = (int*)alloc((size_t)E * 4);
  int* rank_dst = (int*)alloc((size_t)E * 4);
  unsigned short* Mfeat = (unsigned short*)alloc((size_t)Nn * 256 * 2);
  unsigned short* msg = (unsigned short*)alloc((size_t)Nn * 512 * 2);
  unsigned short* h1ln = (unsigned short*)alloc((size_t)Nn * 128 * 2);
  short* WmT = (short*)alloc((size_t)512 * 256 * 2);
  short* W1T = (short*)alloc((size_t)512 * 128 * 2);
  short* W2T = (short*)alloc((size_t)128 * 512 * 2);
  int* off_src = (int*)alloc((size_t)(Nn + 1) * 4);
  int* off_dst = (int*)alloc((size_t)(Nn + 1) * 4);
  int2* pair_src = (int2*)alloc((size_t)E * 8);
  int2* pair_dst = (int2*)alloc((size_t)E * 8);
  int* sumsA = (int*)alloc(64 * 4);
  int* sumsB = (int*)alloc(64 * 4);

  int n1 = (int)((z_end - (char*)combined) >> 2);
  init_kernel<<<1024, 256, 0, stream>>>((unsigned int*)combined, n1, Wm, WmT,
                                        W1, W1T, W2, W2T);

  int gx = (Nn + 63) / 64;           // 313
  int gemmBlocks = gx * 2;           // 626 (NT=2, 2 n-tiles)
  int edgeBlocks = (E + 511) / 512;  // 391 (1 edge/thread)
  int totBlocks = gemmBlocks + edgeBlocks;  // 1017
  // Role-interleaved fused launch: edge and GEMM blocks Bresenham-mixed
  gemm1_edge_kernel<<<totBlocks, 512, 0, stream>>>(
      src_feat, WmT, bm, Mfeat, Nn, edgeBlocks, totBlocks, gate, idx, exp_e,
      combined, deg_dst, rank_src, rank_dst, E, Nn);

  int nb = (Nn + 1023) / 1024;  // 20
  scan_part_kernel<<<nb, 1024, 0, stream>>>(combined, deg_dst, row_sum,
                                            cnt_src0, cnt_dst0, off_src,
                                            off_dst, sumsA, sumsB, Nn);
  scan_fixup_kernel<<<nb, 1024, 0, stream>>>(off_src, off_dst, sumsA, sumsB,
                                             Nn, nb);
  // scatter: NO atomics (replica-rebased ranks), packed int2 pairs
  scatter_ids_kernel<<<(E + 511) / 512, 256, 0, stream>>>(
      idx, exp_e, row_sum, off_src, off_dst, cnt_src0, cnt_dst0, rank_src,
      rank_dst, pair_src, pair_dst, E);
  // aggregate: one wave per (node, dir) -> 40000 waves
  aggregate_kernel<<<(2 * Nn + 3) / 4, 256, 0, stream>>>(
      off_src, pair_src, off_dst, pair_dst, Mfeat, msg, Nn);
  // GEMM2 + LN + ReLU fused: h1ln(bf16) = relu(LN(msg @ W1 + b1))
  gemm2_ln_kernel<<<gx, 512, 0, stream>>>(msg, W1T, b1, gamma, beta, h1ln, Nn);
  // GEMM3: out(f32) = h1ln(bf16) @ W2 + b2, relu+mask  [M=Nn,N=512,K=128],
  //        NT=4, y=2
  mfma_gemm_kernel<1, 1, 4><<<dim3(gx, 2), 512, 0, stream>>>(
      h1ln, W2T, b2, row_sum, out, Nn, 512, 128);
}